// Round 1
// baseline (1297.780 us; speedup 1.0000x reference)
//
#include <hip/hip_runtime.h>

typedef __bf16 bf16;
typedef __bf16 bf16x8 __attribute__((ext_vector_type(8)));
typedef float f32x4 __attribute__((ext_vector_type(4)));

#define L_TOT 110592   // 48^3
#define TOKS  221184   // 2*L
#define NWIN  3456     // 2*12^3

static __device__ __forceinline__ f32x4 mfma16(bf16x8 a, bf16x8 b, f32x4 c) {
    return __builtin_amdgcn_mfma_f32_16x16x32_bf16(a, b, c, 0, 0, 0);
}
static __device__ __forceinline__ bf16x8 ld8(const bf16* p) { return *(const bf16x8*)p; }

// ---------------- setup kernels ----------------
__global__ void wt_transpose(const float* __restrict__ src, bf16* __restrict__ dst, int K, int N) {
    int i = blockIdx.x * 256 + threadIdx.x;
    if (i >= K * N) return;
    int n = i / K, k = i - n * K;
    dst[i] = (bf16)src[k * N + n];
}

__global__ void bias6_build(const float* __restrict__ rpb, float* __restrict__ bias6) {
    int i = blockIdx.x * 256 + threadIdx.x;
    if (i >= 6 * 64 * 64) return;
    int h = i >> 12, n = (i >> 6) & 63, m = i & 63;
    int r0 = (n >> 4) - (m >> 4) + 3;
    int r1 = ((n >> 2) & 3) - ((m >> 2) & 3) + 3;
    int r2 = (n & 3) - (m & 3) + 3;
    bias6[i] = rpb[(r0 * 49 + r1 * 7 + r2) * 6 + h];
}

// ---------------- LN kernels (wave per token, 192 = 3/lane) ----------------
__global__ void ln1_window(const float* __restrict__ x, const float* __restrict__ g,
                           const float* __restrict__ bt, bf16* __restrict__ xw) {
    int wave = threadIdx.x >> 6, lane = threadIdx.x & 63;
    int t = blockIdx.x * 4 + wave;
    const float* row = x + (long)t * 192;
    float v0 = row[lane], v1 = row[lane + 64], v2 = row[lane + 128];
    float s = v0 + v1 + v2;
    #pragma unroll
    for (int m = 1; m < 64; m <<= 1) s += __shfl_xor(s, m);
    float mu = s * (1.0f / 192.0f);
    float d0 = v0 - mu, d1 = v1 - mu, d2 = v2 - mu;
    float q = d0 * d0 + d1 * d1 + d2 * d2;
    #pragma unroll
    for (int m = 1; m < 64; m <<= 1) q += __shfl_xor(q, m);
    float r = rsqrtf(q * (1.0f / 192.0f) + 1e-5f);
    int b = t / L_TOT, l = t - b * L_TOT;
    int dz = l / 2304, rem = l - dz * 2304;
    int hy = rem / 48, wx = rem - hy * 48;
    int w = ((b * 12 + (dz >> 2)) * 12 + (hy >> 2)) * 12 + (wx >> 2);
    int n = (dz & 3) * 16 + (hy & 3) * 4 + (wx & 3);
    bf16* o = xw + ((long)(w * 64 + n)) * 192;
    o[lane]       = (bf16)(d0 * r * g[lane]       + bt[lane]);
    o[lane + 64]  = (bf16)(d1 * r * g[lane + 64]  + bt[lane + 64]);
    o[lane + 128] = (bf16)(d2 * r * g[lane + 128] + bt[lane + 128]);
}

__global__ void ln2_kernel(const float* __restrict__ in, const float* __restrict__ g,
                           const float* __restrict__ bt, bf16* __restrict__ y) {
    int wave = threadIdx.x >> 6, lane = threadIdx.x & 63;
    long t = blockIdx.x * 4 + wave;
    const float* row = in + t * 192;
    float v0 = row[lane], v1 = row[lane + 64], v2 = row[lane + 128];
    float s = v0 + v1 + v2;
    #pragma unroll
    for (int m = 1; m < 64; m <<= 1) s += __shfl_xor(s, m);
    float mu = s * (1.0f / 192.0f);
    float d0 = v0 - mu, d1 = v1 - mu, d2 = v2 - mu;
    float q = d0 * d0 + d1 * d1 + d2 * d2;
    #pragma unroll
    for (int m = 1; m < 64; m <<= 1) q += __shfl_xor(q, m);
    float r = rsqrtf(q * (1.0f / 192.0f) + 1e-5f);
    bf16* o = y + t * 192;
    o[lane]       = (bf16)(d0 * r * g[lane]       + bt[lane]);
    o[lane + 64]  = (bf16)(d1 * r * g[lane + 64]  + bt[lane + 64]);
    o[lane + 128] = (bf16)(d2 * r * g[lane + 128] + bt[lane + 128]);
}

// ---------------- fused window attention: block=window, wave=head ----------------
__global__ __launch_bounds__(384) void attn_fused(
    const bf16* __restrict__ xw, const bf16* __restrict__ wqkv_t,
    const float* __restrict__ bqkv, const float* __restrict__ bias6,
    bf16* __restrict__ aw) {
    int w = blockIdx.x;
    int h = threadIdx.x >> 6;
    int lane = threadIdx.x & 63;
    int lo = lane & 15, hi = lane >> 4;
    extern __shared__ char smem[];
    bf16* q_lds  = (bf16*)(smem + h * 12288); // [64][32] bf16 (4KB)
    bf16* k_lds  = q_lds + 2048;              // [64][32]
    bf16* p_lds  = q_lds;                     // [64][64] overlays q+k after S
    bf16* vt_lds = q_lds + 4096;              // [32][64] V transposed

    const bf16* A = xw + (long)w * 64 * 192;
    f32x4 zf = {0.f, 0.f, 0.f, 0.f};
    f32x4 aq[4][2], ak[4][2], av[4][2];
    #pragma unroll
    for (int i = 0; i < 4; ++i)
        #pragma unroll
        for (int j = 0; j < 2; ++j) { aq[i][j] = zf; ak[i][j] = zf; av[i][j] = zf; }

    #pragma unroll
    for (int ks = 0; ks < 6; ++ks) {
        bf16x8 a[4];
        #pragma unroll
        for (int ti = 0; ti < 4; ++ti)
            a[ti] = ld8(A + (ti * 16 + lo) * 192 + ks * 32 + hi * 8);
        #pragma unroll
        for (int tj = 0; tj < 2; ++tj) {
            bf16x8 bq = ld8(wqkv_t + (long)(      h * 32 + tj * 16 + lo) * 192 + ks * 32 + hi * 8);
            bf16x8 bk = ld8(wqkv_t + (long)(192 + h * 32 + tj * 16 + lo) * 192 + ks * 32 + hi * 8);
            bf16x8 bv = ld8(wqkv_t + (long)(384 + h * 32 + tj * 16 + lo) * 192 + ks * 32 + hi * 8);
            #pragma unroll
            for (int ti = 0; ti < 4; ++ti) {
                aq[ti][tj] = mfma16(a[ti], bq, aq[ti][tj]);
                ak[ti][tj] = mfma16(a[ti], bk, ak[ti][tj]);
                av[ti][tj] = mfma16(a[ti], bv, av[ti][tj]);
            }
        }
    }
    // epilogue -> LDS (Q scaled)
    #pragma unroll
    for (int ti = 0; ti < 4; ++ti)
        #pragma unroll
        for (int tj = 0; tj < 2; ++tj)
            #pragma unroll
            for (int j = 0; j < 4; ++j) {
                int rr = ti * 16 + hi * 4 + j;
                int cc = tj * 16 + lo;
                q_lds[rr * 32 + cc]  = (bf16)((aq[ti][tj][j] + bqkv[h * 32 + cc]) * 0.17677669529663687f);
                k_lds[rr * 32 + cc]  = (bf16)(ak[ti][tj][j] + bqkv[192 + h * 32 + cc]);
                vt_lds[cc * 64 + rr] = (bf16)(av[ti][tj][j] + bqkv[384 + h * 32 + cc]);
            }
    __syncthreads();

    // S = Q K^T (64x64) per head
    f32x4 s[4][4];
    bf16x8 qa[4], kb[4];
    #pragma unroll
    for (int ti = 0; ti < 4; ++ti) qa[ti] = ld8(q_lds + (ti * 16 + lo) * 32 + hi * 8);
    #pragma unroll
    for (int tj = 0; tj < 4; ++tj) kb[tj] = ld8(k_lds + (tj * 16 + lo) * 32 + hi * 8);
    #pragma unroll
    for (int ti = 0; ti < 4; ++ti)
        #pragma unroll
        for (int tj = 0; tj < 4; ++tj)
            s[ti][tj] = mfma16(qa[ti], kb[tj], zf);
    __syncthreads();  // q/k reads done before P overwrite

    // bias + softmax (rows: 16-lane groups)
    const float* bh = bias6 + h * 4096;
    #pragma unroll
    for (int ti = 0; ti < 4; ++ti)
        #pragma unroll
        for (int j = 0; j < 4; ++j) {
            int rr = ti * 16 + hi * 4 + j;
            float ev[4];
            #pragma unroll
            for (int tj = 0; tj < 4; ++tj) s[ti][tj][j] += bh[rr * 64 + tj * 16 + lo];
            float mx = fmaxf(fmaxf(s[ti][0][j], s[ti][1][j]), fmaxf(s[ti][2][j], s[ti][3][j]));
            #pragma unroll
            for (int m = 1; m < 16; m <<= 1) mx = fmaxf(mx, __shfl_xor(mx, m));
            float sum = 0.f;
            #pragma unroll
            for (int tj = 0; tj < 4; ++tj) { ev[tj] = __expf(s[ti][tj][j] - mx); sum += ev[tj]; }
            #pragma unroll
            for (int m = 1; m < 16; m <<= 1) sum += __shfl_xor(sum, m);
            float inv = 1.0f / sum;
            #pragma unroll
            for (int tj = 0; tj < 4; ++tj) p_lds[rr * 64 + tj * 16 + lo] = (bf16)(ev[tj] * inv);
        }
    __syncthreads();

    // O = P V  (64x32)
    f32x4 o[4][2];
    #pragma unroll
    for (int i = 0; i < 4; ++i) { o[i][0] = zf; o[i][1] = zf; }
    #pragma unroll
    for (int ks2 = 0; ks2 < 2; ++ks2) {
        bf16x8 pa[4], vb[2];
        #pragma unroll
        for (int ti = 0; ti < 4; ++ti) pa[ti] = ld8(p_lds + (ti * 16 + lo) * 64 + ks2 * 32 + hi * 8);
        #pragma unroll
        for (int td = 0; td < 2; ++td) vb[td] = ld8(vt_lds + (td * 16 + lo) * 64 + ks2 * 32 + hi * 8);
        #pragma unroll
        for (int ti = 0; ti < 4; ++ti)
            #pragma unroll
            for (int td = 0; td < 2; ++td)
                o[ti][td] = mfma16(pa[ti], vb[td], o[ti][td]);
    }
    bf16* orow = aw + (long)w * 64 * 192 + h * 32;
    #pragma unroll
    for (int ti = 0; ti < 4; ++ti)
        #pragma unroll
        for (int td = 0; td < 2; ++td)
            #pragma unroll
            for (int j = 0; j < 4; ++j)
                orow[(ti * 16 + hi * 4 + j) * 192 + td * 16 + lo] = (bf16)o[ti][td][j];
}

// ---------------- proj GEMM + unwindow + residual ----------------
__global__ __launch_bounds__(256) void gemm_proj(
    const bf16* __restrict__ aw, const bf16* __restrict__ wt,
    const float* __restrict__ bias, const float* __restrict__ x,
    float* __restrict__ out1) {
    int n0 = blockIdx.x * 64, m0 = blockIdx.y * 128;
    int wid = threadIdx.x >> 6, lane = threadIdx.x & 63;
    int wr = wid >> 1, wc = wid & 1;
    int lo = lane & 15, hi = lane >> 4;
    f32x4 zf = {0.f, 0.f, 0.f, 0.f};
    f32x4 acc[4][2];
    #pragma unroll
    for (int i = 0; i < 4; ++i) { acc[i][0] = zf; acc[i][1] = zf; }
    const bf16* Ab = aw + (long)(m0 + wr * 64 + lo) * 192;
    const bf16* Bb = wt + (long)(n0 + wc * 32 + lo) * 192;
    #pragma unroll
    for (int ks = 0; ks < 6; ++ks) {
        bf16x8 a[4], bfr[2];
        #pragma unroll
        for (int ti = 0; ti < 4; ++ti) a[ti] = ld8(Ab + ti * 16 * 192 + ks * 32 + hi * 8);
        #pragma unroll
        for (int tj = 0; tj < 2; ++tj) bfr[tj] = ld8(Bb + tj * 16 * 192 + ks * 32 + hi * 8);
        #pragma unroll
        for (int ti = 0; ti < 4; ++ti)
            #pragma unroll
            for (int tj = 0; tj < 2; ++tj)
                acc[ti][tj] = mfma16(a[ti], bfr[tj], acc[ti][tj]);
    }
    #pragma unroll
    for (int ti = 0; ti < 4; ++ti)
        #pragma unroll
        for (int j = 0; j < 4; ++j) {
            int trow = m0 + wr * 64 + ti * 16 + hi * 4 + j;
            int wv = trow >> 6, n = trow & 63;
            int bb = wv / 1728; int rem = wv - bb * 1728;
            int dq = rem / 144; int rem2 = rem - dq * 144;
            int hq = rem2 / 12; int wq = rem2 - hq * 12;
            int l = (dq * 4 + (n >> 4)) * 2304 + (hq * 4 + ((n >> 2) & 3)) * 48 + (wq * 4 + (n & 3));
            long base = ((long)bb * L_TOT + l) * 192;
            #pragma unroll
            for (int tj = 0; tj < 2; ++tj) {
                int col = n0 + wc * 32 + tj * 16 + lo;
                out1[base + col] = x[base + col] + acc[ti][tj][j] + bias[col];
            }
        }
}

// ---------------- fc1 GEMM (transpose epilogue -> channel-major h_t) ----------------
__global__ __launch_bounds__(256) void gemm_fc1(
    const bf16* __restrict__ y, const bf16* __restrict__ wt,
    const float* __restrict__ bias, bf16* __restrict__ h_t) {
    __shared__ bf16 tl[64][132];
    int n0 = blockIdx.x * 64, m0 = blockIdx.y * 128;
    int wid = threadIdx.x >> 6, lane = threadIdx.x & 63;
    int wr = wid >> 1, wc = wid & 1;
    int lo = lane & 15, hi = lane >> 4;
    f32x4 zf = {0.f, 0.f, 0.f, 0.f};
    f32x4 acc[4][2];
    #pragma unroll
    for (int i = 0; i < 4; ++i) { acc[i][0] = zf; acc[i][1] = zf; }
    const bf16* Ab = y + (long)(m0 + wr * 64 + lo) * 192;
    const bf16* Bb = wt + (long)(n0 + wc * 32 + lo) * 192;
    #pragma unroll
    for (int ks = 0; ks < 6; ++ks) {
        bf16x8 a[4], bfr[2];
        #pragma unroll
        for (int ti = 0; ti < 4; ++ti) a[ti] = ld8(Ab + ti * 16 * 192 + ks * 32 + hi * 8);
        #pragma unroll
        for (int tj = 0; tj < 2; ++tj) bfr[tj] = ld8(Bb + tj * 16 * 192 + ks * 32 + hi * 8);
        #pragma unroll
        for (int ti = 0; ti < 4; ++ti)
            #pragma unroll
            for (int tj = 0; tj < 2; ++tj)
                acc[ti][tj] = mfma16(a[ti], bfr[tj], acc[ti][tj]);
    }
    #pragma unroll
    for (int ti = 0; ti < 4; ++ti)
        #pragma unroll
        for (int tj = 0; tj < 2; ++tj)
            #pragma unroll
            for (int j = 0; j < 4; ++j) {
                int rl = wr * 64 + ti * 16 + hi * 4 + j;
                int cl = wc * 32 + tj * 16 + lo;
                tl[cl][rl] = (bf16)(acc[ti][tj][j] + bias[n0 + cl]);
            }
    __syncthreads();
    int bb = m0 / L_TOT; int l0 = m0 - bb * L_TOT;
    int col = threadIdx.x >> 2, seg = threadIdx.x & 3;
    bf16* dst = h_t + ((long)bb * 384 + n0 + col) * L_TOT + l0 + seg * 32;
    #pragma unroll
    for (int i = 0; i < 32; ++i) dst[i] = tl[col][seg * 32 + i];
}

// ---------------- depthwise conv 3^3 + BN + GELU (channel-major) ----------------
__global__ __launch_bounds__(256) void dwconv_bn_gelu(
    const bf16* __restrict__ h_t, const float* __restrict__ wconv,
    const float* __restrict__ cb, const float* __restrict__ bng,
    const float* __restrict__ bnb, const float* __restrict__ bnm,
    const float* __restrict__ bnv, bf16* __restrict__ g_t) {
    __shared__ __align__(16) bf16 tile[10 * 2304];
    int blk = blockIdx.x;
    int bb = blk / 2304; int rem = blk - bb * 2304;
    int ch = rem / 6; int zb = rem - ch * 6; int z0 = zb * 8;
    const bf16* src = h_t + ((long)bb * 384 + ch) * L_TOT;
    for (int c = threadIdx.x; c < 2880; c += 256) {
        int e = c * 8; int zi = e / 2304; int off = e - zi * 2304;
        int gz = z0 - 1 + zi;
        uint4 val = make_uint4(0u, 0u, 0u, 0u);
        if (gz >= 0 && gz < 48) val = *(const uint4*)(src + (long)gz * 2304 + off);
        *(uint4*)(tile + e) = val;
    }
    float wr_[27];
    #pragma unroll
    for (int i = 0; i < 27; ++i) wr_[i] = wconv[ch * 27 + i];
    float scale = bng[ch] * rsqrtf(bnv[ch] + 1e-5f);
    float shift = bnb[ch] - bnm[ch] * scale;
    float cbias = cb[ch];
    __syncthreads();
    bf16* dst = g_t + ((long)bb * 384 + ch) * L_TOT + (long)z0 * 2304;
    #pragma unroll
    for (int u = 0; u < 3; ++u) {
        int unit = threadIdx.x + u * 256;
        int z = unit / 96; int r2 = unit - z * 96;
        int yy = r2 >> 1; int x0 = (r2 & 1) * 24;
        float acc[24];
        #pragma unroll
        for (int i = 0; i < 24; ++i) acc[i] = 0.f;
        #pragma unroll
        for (int dz = 0; dz < 3; ++dz) {
            const bf16* zbase = tile + (z + dz) * 2304;
            #pragma unroll
            for (int dy = 0; dy < 3; ++dy) {
                int ys = yy + dy - 1;
                if (ys < 0 || ys >= 48) continue;
                const bf16* rb = zbase + ys * 48;
                float row[26];
                #pragma unroll
                for (int i = 0; i < 26; ++i) {
                    int xx = x0 + i - 1;
                    row[i] = (xx >= 0 && xx < 48) ? (float)rb[xx] : 0.0f;
                }
                float w0 = wr_[dz * 9 + dy * 3 + 0];
                float w1 = wr_[dz * 9 + dy * 3 + 1];
                float w2 = wr_[dz * 9 + dy * 3 + 2];
                #pragma unroll
                for (int xi = 0; xi < 24; ++xi)
                    acc[xi] = fmaf(w0, row[xi], fmaf(w1, row[xi + 1], fmaf(w2, row[xi + 2], acc[xi])));
            }
        }
        #pragma unroll
        for (int xi = 0; xi < 24; ++xi) {
            float v = acc[xi] + cbias;
            v = v * scale + shift;
            float gl = 0.5f * v * (1.0f + erff(v * 0.70710678118654752f));
            dst[z * 2304 + yy * 48 + x0 + xi] = (bf16)gl;
        }
    }
}

// ---------------- fc2 GEMM (LDS-staged transposed A) + final residual ----------------
__global__ __launch_bounds__(256) void gemm_fc2(
    const bf16* __restrict__ g_t, const bf16* __restrict__ wt,
    const float* __restrict__ bias, const float* __restrict__ out1,
    float* __restrict__ out) {
    __shared__ bf16 As[128][40];
    int n0 = blockIdx.x * 64, m0 = blockIdx.y * 128;
    int wid = threadIdx.x >> 6, lane = threadIdx.x & 63;
    int wr = wid >> 1, wc = wid & 1;
    int lo = lane & 15, hi = lane >> 4;
    int bb = m0 / L_TOT, l0 = m0 - bb * L_TOT;
    f32x4 zf = {0.f, 0.f, 0.f, 0.f};
    f32x4 acc[4][2];
    #pragma unroll
    for (int i = 0; i < 4; ++i) { acc[i][0] = zf; acc[i][1] = zf; }
    const bf16* gbase = g_t + (long)bb * 384 * L_TOT + l0;
    int kk = threadIdx.x >> 3, seg = threadIdx.x & 7;
    for (int ks = 0; ks < 12; ++ks) {
        __syncthreads();
        const bf16* sp = gbase + (long)(ks * 32 + kk) * L_TOT + seg * 16;
        #pragma unroll
        for (int i = 0; i < 16; ++i) As[seg * 16 + i][kk] = sp[i];
        __syncthreads();
        bf16x8 a[4], bfr[2];
        #pragma unroll
        for (int ti = 0; ti < 4; ++ti) a[ti] = *(const bf16x8*)(&As[wr * 64 + ti * 16 + lo][hi * 8]);
        #pragma unroll
        for (int tj = 0; tj < 2; ++tj)
            bfr[tj] = ld8(wt + (long)(n0 + wc * 32 + tj * 16 + lo) * 384 + ks * 32 + hi * 8);
        #pragma unroll
        for (int ti = 0; ti < 4; ++ti)
            #pragma unroll
            for (int tj = 0; tj < 2; ++tj)
                acc[ti][tj] = mfma16(a[ti], bfr[tj], acc[ti][tj]);
    }
    #pragma unroll
    for (int ti = 0; ti < 4; ++ti)
        #pragma unroll
        for (int j = 0; j < 4; ++j) {
            long trow = m0 + wr * 64 + ti * 16 + hi * 4 + j;
            long base = trow * 192;
            #pragma unroll
            for (int tj = 0; tj < 2; ++tj) {
                int col = n0 + wc * 32 + tj * 16 + lo;
                out[base + col] = out1[base + col] + acc[ti][tj][j] + bias[col];
            }
        }
}

// ---------------- host ----------------
extern "C" void kernel_launch(void* const* d_in, const int* in_sizes, int n_in,
                              void* d_out, int out_size, void* d_ws, size_t ws_size,
                              hipStream_t stream) {
    (void)in_sizes; (void)n_in; (void)out_size; (void)ws_size;
    const float* x     = (const float*)d_in[0];
    const float* ln1g  = (const float*)d_in[4];
    const float* ln1b  = (const float*)d_in[5];
    const float* ln2g  = (const float*)d_in[6];
    const float* ln2b  = (const float*)d_in[7];
    const float* qkvw  = (const float*)d_in[8];
    const float* qkvb  = (const float*)d_in[9];
    const float* rpb   = (const float*)d_in[10];
    const float* projw = (const float*)d_in[11];
    const float* projb = (const float*)d_in[12];
    const float* fc1w  = (const float*)d_in[13];
    const float* fc1b  = (const float*)d_in[14];
    const float* dww   = (const float*)d_in[15];
    const float* dwb   = (const float*)d_in[16];
    const float* bng   = (const float*)d_in[17];
    const float* bnb   = (const float*)d_in[18];
    const float* bnm   = (const float*)d_in[19];
    const float* bnv   = (const float*)d_in[20];
    const float* fc2w  = (const float*)d_in[21];
    const float* fc2b  = (const float*)d_in[22];
    float* out = (float*)d_out;

    char* ws = (char*)d_ws;
    size_t o = 0;
    float* out1 = (float*)(ws + o); o += 169869312;          // f32 [2][L][192]
    bf16*  h_t  = (bf16*)(ws + o); o += 169869312;           // bf16 [2][384][L]
    bf16*  region1 = (bf16*)(ws + o); o += 169869312;        // xw|aw -> y -> g_t
    bf16*  xw  = region1;
    bf16*  aw  = region1 + 42467328;                          // elements
    bf16*  yb  = region1;                                     // reuses xw after attn
    bf16*  g_t = region1;                                     // reuses whole region after fc1
    bf16*  qkvwt  = (bf16*)(ws + o); o += 221184;
    bf16*  projwt = (bf16*)(ws + o); o += 73728;
    bf16*  fc1wt  = (bf16*)(ws + o); o += 147456;
    bf16*  fc2wt  = (bf16*)(ws + o); o += 147456;
    float* bias6  = (float*)(ws + o); o += 98304;

    wt_transpose<<<(110592 + 255) / 256, 256, 0, stream>>>(qkvw, qkvwt, 192, 576);
    wt_transpose<<<(36864 + 255) / 256, 256, 0, stream>>>(projw, projwt, 192, 192);
    wt_transpose<<<(73728 + 255) / 256, 256, 0, stream>>>(fc1w, fc1wt, 192, 384);
    wt_transpose<<<(73728 + 255) / 256, 256, 0, stream>>>(fc2w, fc2wt, 384, 192);
    bias6_build<<<96, 256, 0, stream>>>(rpb, bias6);

    ln1_window<<<55296, 256, 0, stream>>>(x, ln1g, ln1b, xw);

    hipFuncSetAttribute((const void*)attn_fused, hipFuncAttributeMaxDynamicSharedMemorySize, 73728);
    attn_fused<<<3456, 384, 73728, stream>>>(xw, qkvwt, qkvb, bias6, aw);

    gemm_proj<<<dim3(3, 1728), 256, 0, stream>>>(aw, projwt, projb, x, out1);
    ln2_kernel<<<55296, 256, 0, stream>>>(out1, ln2g, ln2b, yb);
    gemm_fc1<<<dim3(6, 1728), 256, 0, stream>>>(yb, fc1wt, fc1b, h_t);
    dwconv_bn_gelu<<<4608, 256, 0, stream>>>(h_t, dww, dwb, bng, bnb, bnm, bnv, g_t);
    gemm_fc2<<<dim3(3, 1728), 256, 0, stream>>>(g_t, fc2wt, fc2b, out1, out);
}

// Round 2
// 1238.769 us; speedup vs baseline: 1.0476x; 1.0476x over previous
//
#include <hip/hip_runtime.h>

typedef __bf16 bf16;
typedef __bf16 bf16x8 __attribute__((ext_vector_type(8)));
typedef float f32x4 __attribute__((ext_vector_type(4)));

#define L_TOT 110592   // 48^3
#define TOKS  221184   // 2*L
#define NWIN  3456     // 2*12^3

static __device__ __forceinline__ f32x4 mfma16(bf16x8 a, bf16x8 b, f32x4 c) {
    return __builtin_amdgcn_mfma_f32_16x16x32_bf16(a, b, c, 0, 0, 0);
}
static __device__ __forceinline__ bf16x8 ld8(const bf16* p) { return *(const bf16x8*)p; }

// ---------------- setup kernels ----------------
__global__ void wt_transpose(const float* __restrict__ src, bf16* __restrict__ dst, int K, int N) {
    int i = blockIdx.x * 256 + threadIdx.x;
    if (i >= K * N) return;
    int n = i / K, k = i - n * K;
    dst[i] = (bf16)src[k * N + n];
}

__global__ void bias6_build(const float* __restrict__ rpb, float* __restrict__ bias6) {
    int i = blockIdx.x * 256 + threadIdx.x;
    if (i >= 6 * 64 * 64) return;
    int h = i >> 12, n = (i >> 6) & 63, m = i & 63;
    int r0 = (n >> 4) - (m >> 4) + 3;
    int r1 = ((n >> 2) & 3) - ((m >> 2) & 3) + 3;
    int r2 = (n & 3) - (m & 3) + 3;
    bias6[i] = rpb[(r0 * 49 + r1 * 7 + r2) * 6 + h];
}

// ---------------- LN kernels (wave per token, 192 = 3/lane) ----------------
__global__ void ln1_window(const float* __restrict__ x, const float* __restrict__ g,
                           const float* __restrict__ bt, bf16* __restrict__ xw) {
    int wave = threadIdx.x >> 6, lane = threadIdx.x & 63;
    int t = blockIdx.x * 4 + wave;
    const float* row = x + (long)t * 192;
    float v0 = row[lane], v1 = row[lane + 64], v2 = row[lane + 128];
    float s = v0 + v1 + v2;
    #pragma unroll
    for (int m = 1; m < 64; m <<= 1) s += __shfl_xor(s, m);
    float mu = s * (1.0f / 192.0f);
    float d0 = v0 - mu, d1 = v1 - mu, d2 = v2 - mu;
    float q = d0 * d0 + d1 * d1 + d2 * d2;
    #pragma unroll
    for (int m = 1; m < 64; m <<= 1) q += __shfl_xor(q, m);
    float r = rsqrtf(q * (1.0f / 192.0f) + 1e-5f);
    int b = t / L_TOT, l = t - b * L_TOT;
    int dz = l / 2304, rem = l - dz * 2304;
    int hy = rem / 48, wx = rem - hy * 48;
    int w = ((b * 12 + (dz >> 2)) * 12 + (hy >> 2)) * 12 + (wx >> 2);
    int n = (dz & 3) * 16 + (hy & 3) * 4 + (wx & 3);
    bf16* o = xw + ((long)(w * 64 + n)) * 192;
    o[lane]       = (bf16)(d0 * r * g[lane]       + bt[lane]);
    o[lane + 64]  = (bf16)(d1 * r * g[lane + 64]  + bt[lane + 64]);
    o[lane + 128] = (bf16)(d2 * r * g[lane + 128] + bt[lane + 128]);
}

__global__ void ln2_kernel(const float* __restrict__ in, const float* __restrict__ g,
                           const float* __restrict__ bt, bf16* __restrict__ y) {
    int wave = threadIdx.x >> 6, lane = threadIdx.x & 63;
    long t = blockIdx.x * 4 + wave;
    const float* row = in + t * 192;
    float v0 = row[lane], v1 = row[lane + 64], v2 = row[lane + 128];
    float s = v0 + v1 + v2;
    #pragma unroll
    for (int m = 1; m < 64; m <<= 1) s += __shfl_xor(s, m);
    float mu = s * (1.0f / 192.0f);
    float d0 = v0 - mu, d1 = v1 - mu, d2 = v2 - mu;
    float q = d0 * d0 + d1 * d1 + d2 * d2;
    #pragma unroll
    for (int m = 1; m < 64; m <<= 1) q += __shfl_xor(q, m);
    float r = rsqrtf(q * (1.0f / 192.0f) + 1e-5f);
    bf16* o = y + t * 192;
    o[lane]       = (bf16)(d0 * r * g[lane]       + bt[lane]);
    o[lane + 64]  = (bf16)(d1 * r * g[lane + 64]  + bt[lane + 64]);
    o[lane + 128] = (bf16)(d2 * r * g[lane + 128] + bt[lane + 128]);
}

// ---------------- QKV GEMM: M=221184, N=576, K=192; epilogue scatters to q/k/vt ----------------
__global__ __launch_bounds__(256) void gemm_qkv(
    const bf16* __restrict__ xw, const bf16* __restrict__ wt,
    const float* __restrict__ bqkv,
    bf16* __restrict__ qb, bf16* __restrict__ kb_, bf16* __restrict__ vtb) {
    int n0 = blockIdx.x * 64, m0 = blockIdx.y * 128;
    int wid = threadIdx.x >> 6, lane = threadIdx.x & 63;
    int wr = wid >> 1, wc = wid & 1;
    int lo = lane & 15, hi = lane >> 4;
    f32x4 zf = {0.f, 0.f, 0.f, 0.f};
    f32x4 acc[4][2];
    #pragma unroll
    for (int i = 0; i < 4; ++i) { acc[i][0] = zf; acc[i][1] = zf; }
    const bf16* Ab = xw + (long)(m0 + wr * 64 + lo) * 192;
    const bf16* Bb = wt + (long)(n0 + wc * 32 + lo) * 192;
    #pragma unroll
    for (int ks = 0; ks < 6; ++ks) {
        bf16x8 a[4], bfr[2];
        #pragma unroll
        for (int ti = 0; ti < 4; ++ti) a[ti] = ld8(Ab + ti * 16 * 192 + ks * 32 + hi * 8);
        #pragma unroll
        for (int tj = 0; tj < 2; ++tj) bfr[tj] = ld8(Bb + tj * 16 * 192 + ks * 32 + hi * 8);
        #pragma unroll
        for (int ti = 0; ti < 4; ++ti)
            #pragma unroll
            for (int tj = 0; tj < 2; ++tj)
                acc[ti][tj] = mfma16(a[ti], bfr[tj], acc[ti][tj]);
    }
    int sect = n0 / 192;            // 0=q 1=k 2=v (uniform per block; 64 | 192)
    int cb0 = n0 - sect * 192;
    #pragma unroll
    for (int ti = 0; ti < 4; ++ti)
        #pragma unroll
        for (int j = 0; j < 4; ++j) {
            int trow = m0 + wr * 64 + ti * 16 + hi * 4 + j;
            int w = trow >> 6, n = trow & 63;
            #pragma unroll
            for (int tj = 0; tj < 2; ++tj) {
                int cw = cb0 + wc * 32 + tj * 16 + lo;   // 0..191 within section
                int h = cw >> 5, d = cw & 31;
                float val = acc[ti][tj][j] + bqkv[sect * 192 + cw];
                long wh = (long)(w * 6 + h);
                if (sect == 0)       qb[(wh * 64 + n) * 32 + d] = (bf16)(val * 0.17677669529663687f);
                else if (sect == 1)  kb_[(wh * 64 + n) * 32 + d] = (bf16)val;
                else                 vtb[(wh * 32 + d) * 64 + n] = (bf16)val;
            }
        }
}

// ---------------- light attention: block=window, wave=head, no barriers ----------------
__global__ __launch_bounds__(384) void attn_light(
    const bf16* __restrict__ qb, const bf16* __restrict__ kb_,
    const bf16* __restrict__ vtb, const float* __restrict__ bias6,
    bf16* __restrict__ aw) {
    __shared__ char p_smem[6 * 8192];   // per head: [64][64] bf16 XOR-swizzled
    int w = blockIdx.x;
    int h = threadIdx.x >> 6;
    int lane = threadIdx.x & 63;
    int lo = lane & 15, hi = lane >> 4;
    char* ph = p_smem + h * 8192;
    long wh = (long)(w * 6 + h);
    f32x4 zf = {0.f, 0.f, 0.f, 0.f};

    // S = Q K^T : fragments straight from global
    bf16x8 qa[4], kb[4];
    #pragma unroll
    for (int ti = 0; ti < 4; ++ti) qa[ti] = ld8(qb  + (wh * 64 + ti * 16 + lo) * 32 + hi * 8);
    #pragma unroll
    for (int tj = 0; tj < 4; ++tj) kb[tj] = ld8(kb_ + (wh * 64 + tj * 16 + lo) * 32 + hi * 8);
    f32x4 s[4][4];
    #pragma unroll
    for (int ti = 0; ti < 4; ++ti)
        #pragma unroll
        for (int tj = 0; tj < 4; ++tj)
            s[ti][tj] = mfma16(qa[ti], kb[tj], zf);

    // bias + softmax (rows live in 16-lane groups), P -> swizzled LDS
    const float* bh = bias6 + h * 4096;
    #pragma unroll
    for (int ti = 0; ti < 4; ++ti)
        #pragma unroll
        for (int j = 0; j < 4; ++j) {
            int rr = ti * 16 + hi * 4 + j;
            float ev[4];
            #pragma unroll
            for (int tj = 0; tj < 4; ++tj) s[ti][tj][j] += bh[rr * 64 + tj * 16 + lo];
            float mx = fmaxf(fmaxf(s[ti][0][j], s[ti][1][j]), fmaxf(s[ti][2][j], s[ti][3][j]));
            #pragma unroll
            for (int m = 1; m < 16; m <<= 1) mx = fmaxf(mx, __shfl_xor(mx, m));
            float sum = 0.f;
            #pragma unroll
            for (int tj = 0; tj < 4; ++tj) { ev[tj] = __expf(s[ti][tj][j] - mx); sum += ev[tj]; }
            #pragma unroll
            for (int m = 1; m < 16; m <<= 1) sum += __shfl_xor(sum, m);
            float inv = 1.0f / sum;
            #pragma unroll
            for (int tj = 0; tj < 4; ++tj) {
                int byte = ((rr * 64 + tj * 16 + lo) * 2) ^ ((rr & 7) << 4);
                *(bf16*)(ph + byte) = (bf16)(ev[tj] * inv);
            }
        }
    // no __syncthreads: P produced and consumed by the same wave

    // O = P V  (64x32), V^T fragments straight from global
    f32x4 o[4][2];
    #pragma unroll
    for (int i = 0; i < 4; ++i) { o[i][0] = zf; o[i][1] = zf; }
    #pragma unroll
    for (int ks2 = 0; ks2 < 2; ++ks2) {
        bf16x8 pa[4], vb[2];
        #pragma unroll
        for (int ti = 0; ti < 4; ++ti) {
            int row = ti * 16 + lo;
            pa[ti] = *(const bf16x8*)(ph + ((row * 128 + ks2 * 64 + hi * 16) ^ ((row & 7) << 4)));
        }
        #pragma unroll
        for (int td = 0; td < 2; ++td)
            vb[td] = ld8(vtb + (wh * 32 + td * 16 + lo) * 64 + ks2 * 32 + hi * 8);
        #pragma unroll
        for (int ti = 0; ti < 4; ++ti)
            #pragma unroll
            for (int td = 0; td < 2; ++td)
                o[ti][td] = mfma16(pa[ti], vb[td], o[ti][td]);
    }
    bf16* orow = aw + (long)w * 64 * 192 + h * 32;
    #pragma unroll
    for (int ti = 0; ti < 4; ++ti)
        #pragma unroll
        for (int td = 0; td < 2; ++td)
            #pragma unroll
            for (int j = 0; j < 4; ++j)
                orow[(ti * 16 + hi * 4 + j) * 192 + td * 16 + lo] = (bf16)o[ti][td][j];
}

// ---------------- proj GEMM + unwindow + residual ----------------
__global__ __launch_bounds__(256) void gemm_proj(
    const bf16* __restrict__ aw, const bf16* __restrict__ wt,
    const float* __restrict__ bias, const float* __restrict__ x,
    float* __restrict__ out1) {
    int n0 = blockIdx.x * 64, m0 = blockIdx.y * 128;
    int wid = threadIdx.x >> 6, lane = threadIdx.x & 63;
    int wr = wid >> 1, wc = wid & 1;
    int lo = lane & 15, hi = lane >> 4;
    f32x4 zf = {0.f, 0.f, 0.f, 0.f};
    f32x4 acc[4][2];
    #pragma unroll
    for (int i = 0; i < 4; ++i) { acc[i][0] = zf; acc[i][1] = zf; }
    const bf16* Ab = aw + (long)(m0 + wr * 64 + lo) * 192;
    const bf16* Bb = wt + (long)(n0 + wc * 32 + lo) * 192;
    #pragma unroll
    for (int ks = 0; ks < 6; ++ks) {
        bf16x8 a[4], bfr[2];
        #pragma unroll
        for (int ti = 0; ti < 4; ++ti) a[ti] = ld8(Ab + ti * 16 * 192 + ks * 32 + hi * 8);
        #pragma unroll
        for (int tj = 0; tj < 2; ++tj) bfr[tj] = ld8(Bb + tj * 16 * 192 + ks * 32 + hi * 8);
        #pragma unroll
        for (int ti = 0; ti < 4; ++ti)
            #pragma unroll
            for (int tj = 0; tj < 2; ++tj)
                acc[ti][tj] = mfma16(a[ti], bfr[tj], acc[ti][tj]);
    }
    #pragma unroll
    for (int ti = 0; ti < 4; ++ti)
        #pragma unroll
        for (int j = 0; j < 4; ++j) {
            int trow = m0 + wr * 64 + ti * 16 + hi * 4 + j;
            int wv = trow >> 6, n = trow & 63;
            int bb = wv / 1728; int rem = wv - bb * 1728;
            int dq = rem / 144; int rem2 = rem - dq * 144;
            int hq = rem2 / 12; int wq = rem2 - hq * 12;
            int l = (dq * 4 + (n >> 4)) * 2304 + (hq * 4 + ((n >> 2) & 3)) * 48 + (wq * 4 + (n & 3));
            long base = ((long)bb * L_TOT + l) * 192;
            #pragma unroll
            for (int tj = 0; tj < 2; ++tj) {
                int col = n0 + wc * 32 + tj * 16 + lo;
                out1[base + col] = x[base + col] + acc[ti][tj][j] + bias[col];
            }
        }
}

// ---------------- fc1 GEMM (transpose epilogue -> channel-major h_t) ----------------
__global__ __launch_bounds__(256) void gemm_fc1(
    const bf16* __restrict__ y, const bf16* __restrict__ wt,
    const float* __restrict__ bias, bf16* __restrict__ h_t) {
    __shared__ bf16 tl[64][132];
    int n0 = blockIdx.x * 64, m0 = blockIdx.y * 128;
    int wid = threadIdx.x >> 6, lane = threadIdx.x & 63;
    int wr = wid >> 1, wc = wid & 1;
    int lo = lane & 15, hi = lane >> 4;
    f32x4 zf = {0.f, 0.f, 0.f, 0.f};
    f32x4 acc[4][2];
    #pragma unroll
    for (int i = 0; i < 4; ++i) { acc[i][0] = zf; acc[i][1] = zf; }
    const bf16* Ab = y + (long)(m0 + wr * 64 + lo) * 192;
    const bf16* Bb = wt + (long)(n0 + wc * 32 + lo) * 192;
    #pragma unroll
    for (int ks = 0; ks < 6; ++ks) {
        bf16x8 a[4], bfr[2];
        #pragma unroll
        for (int ti = 0; ti < 4; ++ti) a[ti] = ld8(Ab + ti * 16 * 192 + ks * 32 + hi * 8);
        #pragma unroll
        for (int tj = 0; tj < 2; ++tj) bfr[tj] = ld8(Bb + tj * 16 * 192 + ks * 32 + hi * 8);
        #pragma unroll
        for (int ti = 0; ti < 4; ++ti)
            #pragma unroll
            for (int tj = 0; tj < 2; ++tj)
                acc[ti][tj] = mfma16(a[ti], bfr[tj], acc[ti][tj]);
    }
    #pragma unroll
    for (int ti = 0; ti < 4; ++ti)
        #pragma unroll
        for (int tj = 0; tj < 2; ++tj)
            #pragma unroll
            for (int j = 0; j < 4; ++j) {
                int rl = wr * 64 + ti * 16 + hi * 4 + j;
                int cl = wc * 32 + tj * 16 + lo;
                tl[cl][rl] = (bf16)(acc[ti][tj][j] + bias[n0 + cl]);
            }
    __syncthreads();
    int bb = m0 / L_TOT; int l0 = m0 - bb * L_TOT;
    int col = threadIdx.x >> 2, seg = threadIdx.x & 3;
    bf16* dst = h_t + ((long)bb * 384 + n0 + col) * L_TOT + l0 + seg * 32;
    #pragma unroll
    for (int i = 0; i < 32; ++i) dst[i] = tl[col][seg * 32 + i];
}

// ---------------- depthwise conv 3^3 + BN + GELU (chunk-vectorized) ----------------
__global__ __launch_bounds__(256) void dwconv_bn_gelu(
    const bf16* __restrict__ h_t, const float* __restrict__ wconv,
    const float* __restrict__ cb, const float* __restrict__ bng,
    const float* __restrict__ bnb, const float* __restrict__ bnm,
    const float* __restrict__ bnv, bf16* __restrict__ g_t) {
    __shared__ __align__(16) bf16 tile[10 * 2304];
    int blk = blockIdx.x;
    int bb = blk / 2304; int rem = blk - bb * 2304;
    int ch = rem / 6; int zb = rem - ch * 6; int z0 = zb * 8;
    const bf16* src = h_t + ((long)bb * 384 + ch) * L_TOT;
    for (int c = threadIdx.x; c < 2880; c += 256) {
        int e = c * 8; int zi = e / 2304; int off = e - zi * 2304;
        int gz = z0 - 1 + zi;
        uint4 val = make_uint4(0u, 0u, 0u, 0u);
        if (gz >= 0 && gz < 48) val = *(const uint4*)(src + (long)gz * 2304 + off);
        *(uint4*)(tile + e) = val;
    }
    float wgt[27];
    #pragma unroll
    for (int i = 0; i < 27; ++i) wgt[i] = wconv[ch * 27 + i];
    float scale = bng[ch] * rsqrtf(bnv[ch] + 1e-5f);
    float shift = bnb[ch] - bnm[ch] * scale;
    float cbias = cb[ch];
    __syncthreads();
    int lane = threadIdx.x & 63;
    bf16* dstc = g_t + ((long)bb * 384 + ch) * L_TOT + (long)z0 * 2304;
    #pragma unroll 1
    for (int u = 0; u < 9; ++u) {
        int unit = threadIdx.x + u * 256;       // consecutive lanes -> consecutive chunks
        int z = unit / 288; int c = unit - z * 288;
        int r = c / 6; int cx = c - r * 6; int x0 = cx * 8;
        float acc[8];
        #pragma unroll
        for (int i = 0; i < 8; ++i) acc[i] = 0.f;
        #pragma unroll
        for (int dz = 0; dz < 3; ++dz) {
            const bf16* plane = tile + (z + dz) * 2304;
            #pragma unroll
            for (int dy = 0; dy < 3; ++dy) {
                int ysr = r + dy - 1;
                bool vld = ((unsigned)ysr < 48u);
                const bf16* rp = plane + (vld ? ysr : 0) * 48 + x0;
                bf16x8 mv = ld8(rp);
                float m[8];
                #pragma unroll
                for (int i = 0; i < 8; ++i) m[i] = (float)mv[i];
                float lf = __shfl_up(m[7], 1);
                if (lane == 0 && cx > 0) lf = (float)rp[-1];
                if (cx == 0) lf = 0.f;
                float rf = __shfl_down(m[0], 1);
                if (lane == 63 && cx < 5) rf = (float)rp[8];
                if (cx == 5) rf = 0.f;
                float W0 = vld ? wgt[dz * 9 + dy * 3 + 0] : 0.f;
                float W1 = vld ? wgt[dz * 9 + dy * 3 + 1] : 0.f;
                float W2 = vld ? wgt[dz * 9 + dy * 3 + 2] : 0.f;
                acc[0] = fmaf(W0, lf,   fmaf(W1, m[0], fmaf(W2, m[1], acc[0])));
                #pragma unroll
                for (int xi = 1; xi < 7; ++xi)
                    acc[xi] = fmaf(W0, m[xi - 1], fmaf(W1, m[xi], fmaf(W2, m[xi + 1], acc[xi])));
                acc[7] = fmaf(W0, m[6], fmaf(W1, m[7], fmaf(W2, rf, acc[7])));
            }
        }
        bf16x8 ov;
        #pragma unroll
        for (int xi = 0; xi < 8; ++xi) {
            float v = acc[xi] + cbias;
            v = v * scale + shift;
            ov[xi] = (bf16)(0.5f * v * (1.0f + erff(v * 0.70710678118654752f)));
        }
        *(bf16x8*)(dstc + z * 2304 + r * 48 + x0) = ov;
    }
}

// ---------------- fc2 GEMM (LDS-staged transposed A) + final residual ----------------
__global__ __launch_bounds__(256) void gemm_fc2(
    const bf16* __restrict__ g_t, const bf16* __restrict__ wt,
    const float* __restrict__ bias, const float* __restrict__ out1,
    float* __restrict__ out) {
    __shared__ bf16 As[128][40];
    int n0 = blockIdx.x * 64, m0 = blockIdx.y * 128;
    int wid = threadIdx.x >> 6, lane = threadIdx.x & 63;
    int wr = wid >> 1, wc = wid & 1;
    int lo = lane & 15, hi = lane >> 4;
    int bb = m0 / L_TOT, l0 = m0 - bb * L_TOT;
    f32x4 zf = {0.f, 0.f, 0.f, 0.f};
    f32x4 acc[4][2];
    #pragma unroll
    for (int i = 0; i < 4; ++i) { acc[i][0] = zf; acc[i][1] = zf; }
    const bf16* gbase = g_t + (long)bb * 384 * L_TOT + l0;
    int kk = threadIdx.x >> 3, seg = threadIdx.x & 7;
    for (int ks = 0; ks < 12; ++ks) {
        __syncthreads();
        const bf16* sp = gbase + (long)(ks * 32 + kk) * L_TOT + seg * 16;
        #pragma unroll
        for (int i = 0; i < 16; ++i) As[seg * 16 + i][kk] = sp[i];
        __syncthreads();
        bf16x8 a[4], bfr[2];
        #pragma unroll
        for (int ti = 0; ti < 4; ++ti) a[ti] = *(const bf16x8*)(&As[wr * 64 + ti * 16 + lo][hi * 8]);
        #pragma unroll
        for (int tj = 0; tj < 2; ++tj)
            bfr[tj] = ld8(wt + (long)(n0 + wc * 32 + tj * 16 + lo) * 384 + ks * 32 + hi * 8);
        #pragma unroll
        for (int ti = 0; ti < 4; ++ti)
            #pragma unroll
            for (int tj = 0; tj < 2; ++tj)
                acc[ti][tj] = mfma16(a[ti], bfr[tj], acc[ti][tj]);
    }
    #pragma unroll
    for (int ti = 0; ti < 4; ++ti)
        #pragma unroll
        for (int j = 0; j < 4; ++j) {
            long trow = m0 + wr * 64 + ti * 16 + hi * 4 + j;
            long base = trow * 192;
            #pragma unroll
            for (int tj = 0; tj < 2; ++tj) {
                int col = n0 + wc * 32 + tj * 16 + lo;
                out[base + col] = out1[base + col] + acc[ti][tj][j] + bias[col];
            }
        }
}

// ---------------- host ----------------
extern "C" void kernel_launch(void* const* d_in, const int* in_sizes, int n_in,
                              void* d_out, int out_size, void* d_ws, size_t ws_size,
                              hipStream_t stream) {
    (void)in_sizes; (void)n_in; (void)out_size; (void)ws_size;
    const float* x     = (const float*)d_in[0];
    const float* ln1g  = (const float*)d_in[4];
    const float* ln1b  = (const float*)d_in[5];
    const float* ln2g  = (const float*)d_in[6];
    const float* ln2b  = (const float*)d_in[7];
    const float* qkvw  = (const float*)d_in[8];
    const float* qkvb  = (const float*)d_in[9];
    const float* rpb   = (const float*)d_in[10];
    const float* projw = (const float*)d_in[11];
    const float* projb = (const float*)d_in[12];
    const float* fc1w  = (const float*)d_in[13];
    const float* fc1b  = (const float*)d_in[14];
    const float* dww   = (const float*)d_in[15];
    const float* dwb   = (const float*)d_in[16];
    const float* bng   = (const float*)d_in[17];
    const float* bnb   = (const float*)d_in[18];
    const float* bnm   = (const float*)d_in[19];
    const float* bnv   = (const float*)d_in[20];
    const float* fc2w  = (const float*)d_in[21];
    const float* fc2b  = (const float*)d_in[22];
    float* out = (float*)d_out;

    char* ws = (char*)d_ws;
    size_t o = 0;
    float* out1 = (float*)(ws + o); o += 169869312;          // f32 [2][L][192]  (first 85MB doubles as vt before proj)
    bf16*  h_t  = (bf16*)(ws + o); o += 169869312;           // bf16 [2][384][L] (doubles as q|k before fc1)
    bf16*  region1 = (bf16*)(ws + o); o += 169869312;        // xw|aw -> y -> g_t
    bf16*  xw  = region1;
    bf16*  aw  = region1 + 42467328;
    bf16*  yb  = region1;
    bf16*  g_t = region1;
    bf16*  qkvwt  = (bf16*)(ws + o); o += 221184;
    bf16*  projwt = (bf16*)(ws + o); o += 73728;
    bf16*  fc1wt  = (bf16*)(ws + o); o += 147456;
    bf16*  fc2wt  = (bf16*)(ws + o); o += 147456;
    float* bias6  = (float*)(ws + o); o += 98304;

    // aliased attention buffers (lifetimes: written by gemm_qkv, dead after attn_light)
    bf16* q_buf  = h_t;                       // 42467328 elems
    bf16* k_buf  = h_t + 42467328;
    bf16* vt_buf = (bf16*)out1;               // dead before gemm_proj writes out1

    wt_transpose<<<(110592 + 255) / 256, 256, 0, stream>>>(qkvw, qkvwt, 192, 576);
    wt_transpose<<<(36864 + 255) / 256, 256, 0, stream>>>(projw, projwt, 192, 192);
    wt_transpose<<<(73728 + 255) / 256, 256, 0, stream>>>(fc1w, fc1wt, 192, 384);
    wt_transpose<<<(73728 + 255) / 256, 256, 0, stream>>>(fc2w, fc2wt, 384, 192);
    bias6_build<<<96, 256, 0, stream>>>(rpb, bias6);

    ln1_window<<<55296, 256, 0, stream>>>(x, ln1g, ln1b, xw);
    gemm_qkv<<<dim3(9, 1728), 256, 0, stream>>>(xw, qkvwt, qkvb, q_buf, k_buf, vt_buf);
    attn_light<<<NWIN, 384, 0, stream>>>(q_buf, k_buf, vt_buf, bias6, aw);
    gemm_proj<<<dim3(3, 1728), 256, 0, stream>>>(aw, projwt, projb, x, out1);
    ln2_kernel<<<55296, 256, 0, stream>>>(out1, ln2g, ln2b, yb);
    gemm_fc1<<<dim3(6, 1728), 256, 0, stream>>>(yb, fc1wt, fc1b, h_t);
    dwconv_bn_gelu<<<4608, 256, 0, stream>>>(h_t, dww, dwb, bng, bnb, bnm, bnv, g_t);
    gemm_fc2<<<dim3(3, 1728), 256, 0, stream>>>(g_t, fc2wt, fc2b, out1, out);
}

// Round 3
// 1018.993 us; speedup vs baseline: 1.2736x; 1.2157x over previous
//
#include <hip/hip_runtime.h>

typedef __bf16 bf16;
typedef __bf16 bf16x8 __attribute__((ext_vector_type(8)));
typedef float f32x4 __attribute__((ext_vector_type(4)));

#define L_TOT 110592   // 48^3
#define TOKS  221184   // 2*L
#define NWIN  3456     // 2*12^3

static __device__ __forceinline__ f32x4 mfma16(bf16x8 a, bf16x8 b, f32x4 c) {
    return __builtin_amdgcn_mfma_f32_16x16x32_bf16(a, b, c, 0, 0, 0);
}
static __device__ __forceinline__ bf16x8 ld8(const bf16* p) { return *(const bf16x8*)p; }

// ---------------- setup kernels ----------------
__global__ void wt_transpose(const float* __restrict__ src, bf16* __restrict__ dst, int K, int N) {
    int i = blockIdx.x * 256 + threadIdx.x;
    if (i >= K * N) return;
    int n = i / K, k = i - n * K;
    dst[i] = (bf16)src[k * N + n];
}

__global__ void bias6_build(const float* __restrict__ rpb, float* __restrict__ bias6) {
    int i = blockIdx.x * 256 + threadIdx.x;
    if (i >= 6 * 64 * 64) return;
    int h = i >> 12, n = (i >> 6) & 63, m = i & 63;
    int r0 = (n >> 4) - (m >> 4) + 3;
    int r1 = ((n >> 2) & 3) - ((m >> 2) & 3) + 3;
    int r2 = (n & 3) - (m & 3) + 3;
    bias6[i] = rpb[(r0 * 49 + r1 * 7 + r2) * 6 + h];
}

// ---------------- LN kernels (wave per token, 192 = 3/lane) ----------------
__global__ void ln1_window(const float* __restrict__ x, const float* __restrict__ g,
                           const float* __restrict__ bt, bf16* __restrict__ xw) {
    int wave = threadIdx.x >> 6, lane = threadIdx.x & 63;
    int t = blockIdx.x * 4 + wave;
    const float* row = x + (long)t * 192;
    float v0 = row[lane], v1 = row[lane + 64], v2 = row[lane + 128];
    float s = v0 + v1 + v2;
    #pragma unroll
    for (int m = 1; m < 64; m <<= 1) s += __shfl_xor(s, m);
    float mu = s * (1.0f / 192.0f);
    float d0 = v0 - mu, d1 = v1 - mu, d2 = v2 - mu;
    float q = d0 * d0 + d1 * d1 + d2 * d2;
    #pragma unroll
    for (int m = 1; m < 64; m <<= 1) q += __shfl_xor(q, m);
    float r = rsqrtf(q * (1.0f / 192.0f) + 1e-5f);
    int b = t / L_TOT, l = t - b * L_TOT;
    int dz = l / 2304, rem = l - dz * 2304;
    int hy = rem / 48, wx = rem - hy * 48;
    int w = ((b * 12 + (dz >> 2)) * 12 + (hy >> 2)) * 12 + (wx >> 2);
    int n = (dz & 3) * 16 + (hy & 3) * 4 + (wx & 3);
    bf16* o = xw + ((long)(w * 64 + n)) * 192;
    o[lane]       = (bf16)(d0 * r * g[lane]       + bt[lane]);
    o[lane + 64]  = (bf16)(d1 * r * g[lane + 64]  + bt[lane + 64]);
    o[lane + 128] = (bf16)(d2 * r * g[lane + 128] + bt[lane + 128]);
}

__global__ void ln2_kernel(const float* __restrict__ in, const float* __restrict__ g,
                           const float* __restrict__ bt, bf16* __restrict__ y) {
    int wave = threadIdx.x >> 6, lane = threadIdx.x & 63;
    long t = blockIdx.x * 4 + wave;
    const float* row = in + t * 192;
    float v0 = row[lane], v1 = row[lane + 64], v2 = row[lane + 128];
    float s = v0 + v1 + v2;
    #pragma unroll
    for (int m = 1; m < 64; m <<= 1) s += __shfl_xor(s, m);
    float mu = s * (1.0f / 192.0f);
    float d0 = v0 - mu, d1 = v1 - mu, d2 = v2 - mu;
    float q = d0 * d0 + d1 * d1 + d2 * d2;
    #pragma unroll
    for (int m = 1; m < 64; m <<= 1) q += __shfl_xor(q, m);
    float r = rsqrtf(q * (1.0f / 192.0f) + 1e-5f);
    bf16* o = y + t * 192;
    o[lane]       = (bf16)(d0 * r * g[lane]       + bt[lane]);
    o[lane + 64]  = (bf16)(d1 * r * g[lane + 64]  + bt[lane + 64]);
    o[lane + 128] = (bf16)(d2 * r * g[lane + 128] + bt[lane + 128]);
}

// ---------------- QKV GEMM: A-fragments register-resident, loop all 9 N-chunks ----------------
__global__ __launch_bounds__(256) void gemm_qkv(
    const bf16* __restrict__ xw, const bf16* __restrict__ wt,
    const float* __restrict__ bqkv,
    bf16* __restrict__ qb, bf16* __restrict__ kb_, bf16* __restrict__ vtb) {
    int m0 = blockIdx.x * 128;
    int wid = threadIdx.x >> 6, lane = threadIdx.x & 63;
    int wr = wid >> 1, wc = wid & 1;
    int lo = lane & 15, hi = lane >> 4;
    f32x4 zf = {0.f, 0.f, 0.f, 0.f};

    const bf16* Ab = xw + (long)(m0 + wr * 64 + lo) * 192 + hi * 8;
    bf16x8 a[4][6];
    #pragma unroll
    for (int ti = 0; ti < 4; ++ti)
        #pragma unroll
        for (int ks = 0; ks < 6; ++ks)
            a[ti][ks] = ld8(Ab + ti * 16 * 192 + ks * 32);

    #pragma unroll
    for (int nc = 0; nc < 9; ++nc) {
        int sect = nc / 3;              // 0=q 1=k 2=v
        int cb0 = (nc - sect * 3) * 64;
        f32x4 acc[4][2];
        #pragma unroll
        for (int i = 0; i < 4; ++i) { acc[i][0] = zf; acc[i][1] = zf; }
        const bf16* Bb = wt + (long)(nc * 64 + wc * 32 + lo) * 192 + hi * 8;
        #pragma unroll
        for (int ks = 0; ks < 6; ++ks) {
            bf16x8 b0 = ld8(Bb + ks * 32);
            bf16x8 b1 = ld8(Bb + 16 * 192 + ks * 32);
            #pragma unroll
            for (int ti = 0; ti < 4; ++ti) {
                acc[ti][0] = mfma16(a[ti][ks], b0, acc[ti][0]);
                acc[ti][1] = mfma16(a[ti][ks], b1, acc[ti][1]);
            }
        }
        #pragma unroll
        for (int ti = 0; ti < 4; ++ti)
            #pragma unroll
            for (int j = 0; j < 4; ++j) {
                int trow = m0 + wr * 64 + ti * 16 + hi * 4 + j;
                int w = trow >> 6, n = trow & 63;
                #pragma unroll
                for (int tj = 0; tj < 2; ++tj) {
                    int cw = cb0 + wc * 32 + tj * 16 + lo;   // 0..191 within section
                    int h = cw >> 5, d = cw & 31;
                    float val = acc[ti][tj][j] + bqkv[sect * 192 + cw];
                    long wh = (long)(w * 6 + h);
                    if (sect == 0)       qb[(wh * 64 + n) * 32 + d] = (bf16)(val * 0.17677669529663687f);
                    else if (sect == 1)  kb_[(wh * 64 + n) * 32 + d] = (bf16)val;
                    else                 vtb[(wh * 32 + d) * 64 + n] = (bf16)val;
                }
            }
    }
}

// ---------------- light attention: block=window, wave=head, no barriers ----------------
__global__ __launch_bounds__(384) void attn_light(
    const bf16* __restrict__ qb, const bf16* __restrict__ kb_,
    const bf16* __restrict__ vtb, const float* __restrict__ bias6,
    bf16* __restrict__ aw) {
    __shared__ char p_smem[6 * 8192];   // per head: [64][64] bf16 XOR-swizzled
    int w = blockIdx.x;
    int h = threadIdx.x >> 6;
    int lane = threadIdx.x & 63;
    int lo = lane & 15, hi = lane >> 4;
    char* ph = p_smem + h * 8192;
    long wh = (long)(w * 6 + h);
    f32x4 zf = {0.f, 0.f, 0.f, 0.f};

    bf16x8 qa[4], kb[4];
    #pragma unroll
    for (int ti = 0; ti < 4; ++ti) qa[ti] = ld8(qb  + (wh * 64 + ti * 16 + lo) * 32 + hi * 8);
    #pragma unroll
    for (int tj = 0; tj < 4; ++tj) kb[tj] = ld8(kb_ + (wh * 64 + tj * 16 + lo) * 32 + hi * 8);
    f32x4 s[4][4];
    #pragma unroll
    for (int ti = 0; ti < 4; ++ti)
        #pragma unroll
        for (int tj = 0; tj < 4; ++tj)
            s[ti][tj] = mfma16(qa[ti], kb[tj], zf);

    const float* bh = bias6 + h * 4096;
    #pragma unroll
    for (int ti = 0; ti < 4; ++ti)
        #pragma unroll
        for (int j = 0; j < 4; ++j) {
            int rr = ti * 16 + hi * 4 + j;
            float ev[4];
            #pragma unroll
            for (int tj = 0; tj < 4; ++tj) s[ti][tj][j] += bh[rr * 64 + tj * 16 + lo];
            float mx = fmaxf(fmaxf(s[ti][0][j], s[ti][1][j]), fmaxf(s[ti][2][j], s[ti][3][j]));
            #pragma unroll
            for (int m = 1; m < 16; m <<= 1) mx = fmaxf(mx, __shfl_xor(mx, m));
            float sum = 0.f;
            #pragma unroll
            for (int tj = 0; tj < 4; ++tj) { ev[tj] = __expf(s[ti][tj][j] - mx); sum += ev[tj]; }
            #pragma unroll
            for (int m = 1; m < 16; m <<= 1) sum += __shfl_xor(sum, m);
            float inv = 1.0f / sum;
            #pragma unroll
            for (int tj = 0; tj < 4; ++tj) {
                int byte = ((rr * 64 + tj * 16 + lo) * 2) ^ ((rr & 7) << 4);
                *(bf16*)(ph + byte) = (bf16)(ev[tj] * inv);
            }
        }

    f32x4 o[4][2];
    #pragma unroll
    for (int i = 0; i < 4; ++i) { o[i][0] = zf; o[i][1] = zf; }
    #pragma unroll
    for (int ks2 = 0; ks2 < 2; ++ks2) {
        bf16x8 pa[4], vb[2];
        #pragma unroll
        for (int ti = 0; ti < 4; ++ti) {
            int row = ti * 16 + lo;
            pa[ti] = *(const bf16x8*)(ph + ((row * 128 + ks2 * 64 + hi * 16) ^ ((row & 7) << 4)));
        }
        #pragma unroll
        for (int td = 0; td < 2; ++td)
            vb[td] = ld8(vtb + (wh * 32 + td * 16 + lo) * 64 + ks2 * 32 + hi * 8);
        #pragma unroll
        for (int ti = 0; ti < 4; ++ti)
            #pragma unroll
            for (int td = 0; td < 2; ++td)
                o[ti][td] = mfma16(pa[ti], vb[td], o[ti][td]);
    }
    bf16* orow = aw + (long)w * 64 * 192 + h * 32;
    #pragma unroll
    for (int ti = 0; ti < 4; ++ti)
        #pragma unroll
        for (int td = 0; td < 2; ++td)
            #pragma unroll
            for (int j = 0; j < 4; ++j)
                orow[(ti * 16 + hi * 4 + j) * 192 + td * 16 + lo] = (bf16)o[ti][td][j];
}

// ---------------- proj GEMM: A resident, 3 N-chunks, unwindow + residual ----------------
__global__ __launch_bounds__(256) void gemm_proj(
    const bf16* __restrict__ aw, const bf16* __restrict__ wt,
    const float* __restrict__ bias, const float* __restrict__ x,
    float* __restrict__ out1) {
    int m0 = blockIdx.x * 128;
    int wid = threadIdx.x >> 6, lane = threadIdx.x & 63;
    int wr = wid >> 1, wc = wid & 1;
    int lo = lane & 15, hi = lane >> 4;
    f32x4 zf = {0.f, 0.f, 0.f, 0.f};

    const bf16* Ab = aw + (long)(m0 + wr * 64 + lo) * 192 + hi * 8;
    bf16x8 a[4][6];
    #pragma unroll
    for (int ti = 0; ti < 4; ++ti)
        #pragma unroll
        for (int ks = 0; ks < 6; ++ks)
            a[ti][ks] = ld8(Ab + ti * 16 * 192 + ks * 32);

    #pragma unroll
    for (int nc = 0; nc < 3; ++nc) {
        f32x4 acc[4][2];
        #pragma unroll
        for (int i = 0; i < 4; ++i) { acc[i][0] = zf; acc[i][1] = zf; }
        const bf16* Bb = wt + (long)(nc * 64 + wc * 32 + lo) * 192 + hi * 8;
        #pragma unroll
        for (int ks = 0; ks < 6; ++ks) {
            bf16x8 b0 = ld8(Bb + ks * 32);
            bf16x8 b1 = ld8(Bb + 16 * 192 + ks * 32);
            #pragma unroll
            for (int ti = 0; ti < 4; ++ti) {
                acc[ti][0] = mfma16(a[ti][ks], b0, acc[ti][0]);
                acc[ti][1] = mfma16(a[ti][ks], b1, acc[ti][1]);
            }
        }
        #pragma unroll
        for (int ti = 0; ti < 4; ++ti)
            #pragma unroll
            for (int j = 0; j < 4; ++j) {
                int trow = m0 + wr * 64 + ti * 16 + hi * 4 + j;
                int wv = trow >> 6, n = trow & 63;
                int bb = wv / 1728; int rem = wv - bb * 1728;
                int dq = rem / 144; int rem2 = rem - dq * 144;
                int hq = rem2 / 12; int wq = rem2 - hq * 12;
                int l = (dq * 4 + (n >> 4)) * 2304 + (hq * 4 + ((n >> 2) & 3)) * 48 + (wq * 4 + (n & 3));
                long base = ((long)bb * L_TOT + l) * 192;
                #pragma unroll
                for (int tj = 0; tj < 2; ++tj) {
                    int col = nc * 64 + wc * 32 + tj * 16 + lo;
                    out1[base + col] = x[base + col] + acc[ti][tj][j] + bias[col];
                }
            }
    }
}

// ---------------- fc1 GEMM: A resident, 6 N-chunks, transpose epilogue ----------------
__global__ __launch_bounds__(256) void gemm_fc1(
    const bf16* __restrict__ y, const bf16* __restrict__ wt,
    const float* __restrict__ bias, bf16* __restrict__ h_t) {
    __shared__ bf16 tl[64][136];
    int m0 = blockIdx.x * 128;
    int wid = threadIdx.x >> 6, lane = threadIdx.x & 63;
    int wr = wid >> 1, wc = wid & 1;
    int lo = lane & 15, hi = lane >> 4;
    f32x4 zf = {0.f, 0.f, 0.f, 0.f};
    int bb = m0 / L_TOT; int l0 = m0 - bb * L_TOT;
    int col = threadIdx.x >> 2, seg = threadIdx.x & 3;

    const bf16* Ab = y + (long)(m0 + wr * 64 + lo) * 192 + hi * 8;
    bf16x8 a[4][6];
    #pragma unroll
    for (int ti = 0; ti < 4; ++ti)
        #pragma unroll
        for (int ks = 0; ks < 6; ++ks)
            a[ti][ks] = ld8(Ab + ti * 16 * 192 + ks * 32);

    #pragma unroll
    for (int nc = 0; nc < 6; ++nc) {
        f32x4 acc[4][2];
        #pragma unroll
        for (int i = 0; i < 4; ++i) { acc[i][0] = zf; acc[i][1] = zf; }
        const bf16* Bb = wt + (long)(nc * 64 + wc * 32 + lo) * 192 + hi * 8;
        #pragma unroll
        for (int ks = 0; ks < 6; ++ks) {
            bf16x8 b0 = ld8(Bb + ks * 32);
            bf16x8 b1 = ld8(Bb + 16 * 192 + ks * 32);
            #pragma unroll
            for (int ti = 0; ti < 4; ++ti) {
                acc[ti][0] = mfma16(a[ti][ks], b0, acc[ti][0]);
                acc[ti][1] = mfma16(a[ti][ks], b1, acc[ti][1]);
            }
        }
        if (nc) __syncthreads();
        #pragma unroll
        for (int ti = 0; ti < 4; ++ti)
            #pragma unroll
            for (int tj = 0; tj < 2; ++tj)
                #pragma unroll
                for (int j = 0; j < 4; ++j) {
                    int rl = wr * 64 + ti * 16 + hi * 4 + j;
                    int cl = wc * 32 + tj * 16 + lo;
                    tl[cl][rl] = (bf16)(acc[ti][tj][j] + bias[nc * 64 + cl]);
                }
        __syncthreads();
        bf16* dst = h_t + ((long)bb * 384 + nc * 64 + col) * L_TOT + l0 + seg * 32;
        #pragma unroll
        for (int i8 = 0; i8 < 4; ++i8)
            *(bf16x8*)(dst + i8 * 8) = *(const bf16x8*)(&tl[col][seg * 32 + i8 * 8]);
    }
}

// ---------------- depthwise conv 3^3 + BN + GELU (chunk-vectorized) ----------------
__global__ __launch_bounds__(256) void dwconv_bn_gelu(
    const bf16* __restrict__ h_t, const float* __restrict__ wconv,
    const float* __restrict__ cb, const float* __restrict__ bng,
    const float* __restrict__ bnb, const float* __restrict__ bnm,
    const float* __restrict__ bnv, bf16* __restrict__ g_t) {
    __shared__ __align__(16) bf16 tile[10 * 2304];
    int blk = blockIdx.x;
    int bb = blk / 2304; int rem = blk - bb * 2304;
    int ch = rem / 6; int zb = rem - ch * 6; int z0 = zb * 8;
    const bf16* src = h_t + ((long)bb * 384 + ch) * L_TOT;
    for (int c = threadIdx.x; c < 2880; c += 256) {
        int e = c * 8; int zi = e / 2304; int off = e - zi * 2304;
        int gz = z0 - 1 + zi;
        uint4 val = make_uint4(0u, 0u, 0u, 0u);
        if (gz >= 0 && gz < 48) val = *(const uint4*)(src + (long)gz * 2304 + off);
        *(uint4*)(tile + e) = val;
    }
    float wgt[27];
    #pragma unroll
    for (int i = 0; i < 27; ++i) wgt[i] = wconv[ch * 27 + i];
    float scale = bng[ch] * rsqrtf(bnv[ch] + 1e-5f);
    float shift = bnb[ch] - bnm[ch] * scale;
    float cbias = cb[ch];
    __syncthreads();
    int lane = threadIdx.x & 63;
    bf16* dstc = g_t + ((long)bb * 384 + ch) * L_TOT + (long)z0 * 2304;
    #pragma unroll 1
    for (int u = 0; u < 9; ++u) {
        int unit = threadIdx.x + u * 256;       // consecutive lanes -> consecutive chunks
        int z = unit / 288; int c = unit - z * 288;
        int r = c / 6; int cx = c - r * 6; int x0 = cx * 8;
        float acc[8];
        #pragma unroll
        for (int i = 0; i < 8; ++i) acc[i] = 0.f;
        #pragma unroll
        for (int dz = 0; dz < 3; ++dz) {
            const bf16* plane = tile + (z + dz) * 2304;
            #pragma unroll
            for (int dy = 0; dy < 3; ++dy) {
                int ysr = r + dy - 1;
                bool vld = ((unsigned)ysr < 48u);
                const bf16* rp = plane + (vld ? ysr : 0) * 48 + x0;
                bf16x8 mv = ld8(rp);
                float m[8];
                #pragma unroll
                for (int i = 0; i < 8; ++i) m[i] = (float)mv[i];
                float lf = __shfl_up(m[7], 1);
                if (lane == 0 && cx > 0) lf = (float)rp[-1];
                if (cx == 0) lf = 0.f;
                float rf = __shfl_down(m[0], 1);
                if (lane == 63 && cx < 5) rf = (float)rp[8];
                if (cx == 5) rf = 0.f;
                float W0 = vld ? wgt[dz * 9 + dy * 3 + 0] : 0.f;
                float W1 = vld ? wgt[dz * 9 + dy * 3 + 1] : 0.f;
                float W2 = vld ? wgt[dz * 9 + dy * 3 + 2] : 0.f;
                acc[0] = fmaf(W0, lf,   fmaf(W1, m[0], fmaf(W2, m[1], acc[0])));
                #pragma unroll
                for (int xi = 1; xi < 7; ++xi)
                    acc[xi] = fmaf(W0, m[xi - 1], fmaf(W1, m[xi], fmaf(W2, m[xi + 1], acc[xi])));
                acc[7] = fmaf(W0, m[6], fmaf(W1, m[7], fmaf(W2, rf, acc[7])));
            }
        }
        bf16x8 ov;
        #pragma unroll
        for (int xi = 0; xi < 8; ++xi) {
            float v = acc[xi] + cbias;
            v = v * scale + shift;
            ov[xi] = (bf16)(0.5f * v * (1.0f + erff(v * 0.70710678118654752f)));
        }
        *(bf16x8*)(dstc + z * 2304 + r * 48 + x0) = ov;
    }
}

// ---------------- fc2 GEMM: stage A per-ks once, 3 N-chunks in regs, + residual ----------------
__global__ __launch_bounds__(256) void gemm_fc2(
    const bf16* __restrict__ g_t, const bf16* __restrict__ wt,
    const float* __restrict__ bias, const float* __restrict__ out1,
    float* __restrict__ out) {
    __shared__ bf16 As[128][40];
    int m0 = blockIdx.x * 128;
    int wid = threadIdx.x >> 6, lane = threadIdx.x & 63;
    int wr = wid >> 1, wc = wid & 1;
    int lo = lane & 15, hi = lane >> 4;
    int bb = m0 / L_TOT, l0 = m0 - bb * L_TOT;
    f32x4 zf = {0.f, 0.f, 0.f, 0.f};
    f32x4 acc[3][4][2];
    #pragma unroll
    for (int nc = 0; nc < 3; ++nc)
        #pragma unroll
        for (int i = 0; i < 4; ++i) { acc[nc][i][0] = zf; acc[nc][i][1] = zf; }
    const bf16* gbase = g_t + (long)bb * 384 * L_TOT + l0;
    int kk = threadIdx.x >> 3, seg = threadIdx.x & 7;
    for (int ks = 0; ks < 12; ++ks) {
        if (ks) __syncthreads();
        const bf16* sp = gbase + (long)(ks * 32 + kk) * L_TOT + seg * 16;
        bf16x8 v0 = ld8(sp), v1 = ld8(sp + 8);
        #pragma unroll
        for (int i = 0; i < 8; ++i) As[seg * 16 + i][kk] = v0[i];
        #pragma unroll
        for (int i = 0; i < 8; ++i) As[seg * 16 + 8 + i][kk] = v1[i];
        __syncthreads();
        bf16x8 a[4];
        #pragma unroll
        for (int ti = 0; ti < 4; ++ti) a[ti] = *(const bf16x8*)(&As[wr * 64 + ti * 16 + lo][hi * 8]);
        #pragma unroll
        for (int nc = 0; nc < 3; ++nc) {
            bf16x8 b0 = ld8(wt + (long)(nc * 64 + wc * 32 + lo) * 384 + ks * 32 + hi * 8);
            bf16x8 b1 = ld8(wt + (long)(nc * 64 + wc * 32 + 16 + lo) * 384 + ks * 32 + hi * 8);
            #pragma unroll
            for (int ti = 0; ti < 4; ++ti) {
                acc[nc][ti][0] = mfma16(a[ti], b0, acc[nc][ti][0]);
                acc[nc][ti][1] = mfma16(a[ti], b1, acc[nc][ti][1]);
            }
        }
    }
    #pragma unroll
    for (int nc = 0; nc < 3; ++nc)
        #pragma unroll
        for (int ti = 0; ti < 4; ++ti)
            #pragma unroll
            for (int j = 0; j < 4; ++j) {
                long trow = m0 + wr * 64 + ti * 16 + hi * 4 + j;
                long base = trow * 192;
                #pragma unroll
                for (int tj = 0; tj < 2; ++tj) {
                    int col = nc * 64 + wc * 32 + tj * 16 + lo;
                    out[base + col] = out1[base + col] + acc[nc][ti][tj][j] + bias[col];
                }
            }
}

// ---------------- host ----------------
extern "C" void kernel_launch(void* const* d_in, const int* in_sizes, int n_in,
                              void* d_out, int out_size, void* d_ws, size_t ws_size,
                              hipStream_t stream) {
    (void)in_sizes; (void)n_in; (void)out_size; (void)ws_size;
    const float* x     = (const float*)d_in[0];
    const float* ln1g  = (const float*)d_in[4];
    const float* ln1b  = (const float*)d_in[5];
    const float* ln2g  = (const float*)d_in[6];
    const float* ln2b  = (const float*)d_in[7];
    const float* qkvw  = (const float*)d_in[8];
    const float* qkvb  = (const float*)d_in[9];
    const float* rpb   = (const float*)d_in[10];
    const float* projw = (const float*)d_in[11];
    const float* projb = (const float*)d_in[12];
    const float* fc1w  = (const float*)d_in[13];
    const float* fc1b  = (const float*)d_in[14];
    const float* dww   = (const float*)d_in[15];
    const float* dwb   = (const float*)d_in[16];
    const float* bng   = (const float*)d_in[17];
    const float* bnb   = (const float*)d_in[18];
    const float* bnm   = (const float*)d_in[19];
    const float* bnv   = (const float*)d_in[20];
    const float* fc2w  = (const float*)d_in[21];
    const float* fc2b  = (const float*)d_in[22];
    float* out = (float*)d_out;

    char* ws = (char*)d_ws;
    size_t o = 0;
    float* out1 = (float*)(ws + o); o += 169869312;          // f32 [2][L][192]  (first 85MB doubles as vt before proj)
    bf16*  h_t  = (bf16*)(ws + o); o += 169869312;           // bf16 [2][384][L] (doubles as q|k before fc1)
    bf16*  region1 = (bf16*)(ws + o); o += 169869312;        // xw|aw -> y -> g_t
    bf16*  xw  = region1;
    bf16*  aw  = region1 + 42467328;
    bf16*  yb  = region1;
    bf16*  g_t = region1;
    bf16*  qkvwt  = (bf16*)(ws + o); o += 221184;
    bf16*  projwt = (bf16*)(ws + o); o += 73728;
    bf16*  fc1wt  = (bf16*)(ws + o); o += 147456;
    bf16*  fc2wt  = (bf16*)(ws + o); o += 147456;
    float* bias6  = (float*)(ws + o); o += 98304;

    bf16* q_buf  = h_t;
    bf16* k_buf  = h_t + 42467328;
    bf16* vt_buf = (bf16*)out1;               // dead before gemm_proj writes out1

    wt_transpose<<<(110592 + 255) / 256, 256, 0, stream>>>(qkvw, qkvwt, 192, 576);
    wt_transpose<<<(36864 + 255) / 256, 256, 0, stream>>>(projw, projwt, 192, 192);
    wt_transpose<<<(73728 + 255) / 256, 256, 0, stream>>>(fc1w, fc1wt, 192, 384);
    wt_transpose<<<(73728 + 255) / 256, 256, 0, stream>>>(fc2w, fc2wt, 384, 192);
    bias6_build<<<96, 256, 0, stream>>>(rpb, bias6);

    ln1_window<<<55296, 256, 0, stream>>>(x, ln1g, ln1b, xw);
    gemm_qkv<<<1728, 256, 0, stream>>>(xw, qkvwt, qkvb, q_buf, k_buf, vt_buf);
    attn_light<<<NWIN, 384, 0, stream>>>(q_buf, k_buf, vt_buf, bias6, aw);
    gemm_proj<<<1728, 256, 0, stream>>>(aw, projwt, projb, x, out1);
    ln2_kernel<<<55296, 256, 0, stream>>>(out1, ln2g, ln2b, yb);
    gemm_fc1<<<1728, 256, 0, stream>>>(yb, fc1wt, fc1b, h_t);
    dwconv_bn_gelu<<<4608, 256, 0, stream>>>(h_t, dww, dwb, bng, bnb, bnm, bnv, g_t);
    gemm_fc2<<<1728, 256, 0, stream>>>(g_t, fc2wt, fc2b, out1, out);
}

// Round 4
// 933.731 us; speedup vs baseline: 1.3899x; 1.0913x over previous
//
#include <hip/hip_runtime.h>

typedef __bf16 bf16;
typedef __bf16 bf16x8 __attribute__((ext_vector_type(8)));
typedef float f32x4 __attribute__((ext_vector_type(4)));

#define L_TOT 110592   // 48^3
#define TOKS  221184   // 2*L
#define NWIN  3456     // 2*12^3

static __device__ __forceinline__ f32x4 mfma16(bf16x8 a, bf16x8 b, f32x4 c) {
    return __builtin_amdgcn_mfma_f32_16x16x32_bf16(a, b, c, 0, 0, 0);
}
static __device__ __forceinline__ bf16x8 ld8(const bf16* p) { return *(const bf16x8*)p; }

// ---------------- setup kernels ----------------
__global__ void wt_transpose(const float* __restrict__ src, bf16* __restrict__ dst, int K, int N) {
    int i = blockIdx.x * 256 + threadIdx.x;
    if (i >= K * N) return;
    int n = i / K, k = i - n * K;
    dst[i] = (bf16)src[k * N + n];
}

__global__ void bias6_build(const float* __restrict__ rpb, float* __restrict__ bias6) {
    int i = blockIdx.x * 256 + threadIdx.x;
    if (i >= 6 * 64 * 64) return;
    int h = i >> 12, n = (i >> 6) & 63, m = i & 63;
    int r0 = (n >> 4) - (m >> 4) + 3;
    int r1 = ((n >> 2) & 3) - ((m >> 2) & 3) + 3;
    int r2 = (n & 3) - (m & 3) + 3;
    bias6[i] = rpb[(r0 * 49 + r1 * 7 + r2) * 6 + h];
}

// ---------------- LN kernels (wave per token, 192 = 3/lane) ----------------
__global__ void ln1_window(const float* __restrict__ x, const float* __restrict__ g,
                           const float* __restrict__ bt, bf16* __restrict__ xw) {
    int wave = threadIdx.x >> 6, lane = threadIdx.x & 63;
    int t = blockIdx.x * 4 + wave;
    const float* row = x + (long)t * 192;
    float v0 = row[lane], v1 = row[lane + 64], v2 = row[lane + 128];
    float s = v0 + v1 + v2;
    #pragma unroll
    for (int m = 1; m < 64; m <<= 1) s += __shfl_xor(s, m);
    float mu = s * (1.0f / 192.0f);
    float d0 = v0 - mu, d1 = v1 - mu, d2 = v2 - mu;
    float q = d0 * d0 + d1 * d1 + d2 * d2;
    #pragma unroll
    for (int m = 1; m < 64; m <<= 1) q += __shfl_xor(q, m);
    float r = rsqrtf(q * (1.0f / 192.0f) + 1e-5f);
    int b = t / L_TOT, l = t - b * L_TOT;
    int dz = l / 2304, rem = l - dz * 2304;
    int hy = rem / 48, wx = rem - hy * 48;
    int w = ((b * 12 + (dz >> 2)) * 12 + (hy >> 2)) * 12 + (wx >> 2);
    int n = (dz & 3) * 16 + (hy & 3) * 4 + (wx & 3);
    bf16* o = xw + ((long)(w * 64 + n)) * 192;
    o[lane]       = (bf16)(d0 * r * g[lane]       + bt[lane]);
    o[lane + 64]  = (bf16)(d1 * r * g[lane + 64]  + bt[lane + 64]);
    o[lane + 128] = (bf16)(d2 * r * g[lane + 128] + bt[lane + 128]);
}

__global__ void ln2_kernel(const bf16* __restrict__ in, const float* __restrict__ g,
                           const float* __restrict__ bt, bf16* __restrict__ y) {
    int wave = threadIdx.x >> 6, lane = threadIdx.x & 63;
    long t = blockIdx.x * 4 + wave;
    const bf16* row = in + t * 192;
    float v0 = (float)row[lane], v1 = (float)row[lane + 64], v2 = (float)row[lane + 128];
    float s = v0 + v1 + v2;
    #pragma unroll
    for (int m = 1; m < 64; m <<= 1) s += __shfl_xor(s, m);
    float mu = s * (1.0f / 192.0f);
    float d0 = v0 - mu, d1 = v1 - mu, d2 = v2 - mu;
    float q = d0 * d0 + d1 * d1 + d2 * d2;
    #pragma unroll
    for (int m = 1; m < 64; m <<= 1) q += __shfl_xor(q, m);
    float r = rsqrtf(q * (1.0f / 192.0f) + 1e-5f);
    bf16* o = y + t * 192;
    o[lane]       = (bf16)(d0 * r * g[lane]       + bt[lane]);
    o[lane + 64]  = (bf16)(d1 * r * g[lane + 64]  + bt[lane + 64]);
    o[lane + 128] = (bf16)(d2 * r * g[lane + 128] + bt[lane + 128]);
}

// ---------------- QKV GEMM: A-fragments register-resident, loop all 9 N-chunks ----------------
__global__ __launch_bounds__(256) void gemm_qkv(
    const bf16* __restrict__ xw, const bf16* __restrict__ wt,
    const float* __restrict__ bqkv,
    bf16* __restrict__ qb, bf16* __restrict__ kb_, bf16* __restrict__ vtb) {
    int m0 = blockIdx.x * 128;
    int wid = threadIdx.x >> 6, lane = threadIdx.x & 63;
    int wr = wid >> 1, wc = wid & 1;
    int lo = lane & 15, hi = lane >> 4;
    f32x4 zf = {0.f, 0.f, 0.f, 0.f};

    const bf16* Ab = xw + (long)(m0 + wr * 64 + lo) * 192 + hi * 8;
    bf16x8 a[4][6];
    #pragma unroll
    for (int ti = 0; ti < 4; ++ti)
        #pragma unroll
        for (int ks = 0; ks < 6; ++ks)
            a[ti][ks] = ld8(Ab + ti * 16 * 192 + ks * 32);

    #pragma unroll
    for (int nc = 0; nc < 9; ++nc) {
        int sect = nc / 3;              // 0=q 1=k 2=v
        int cb0 = (nc - sect * 3) * 64;
        f32x4 acc[4][2];
        #pragma unroll
        for (int i = 0; i < 4; ++i) { acc[i][0] = zf; acc[i][1] = zf; }
        const bf16* Bb = wt + (long)(nc * 64 + wc * 32 + lo) * 192 + hi * 8;
        #pragma unroll
        for (int ks = 0; ks < 6; ++ks) {
            bf16x8 b0 = ld8(Bb + ks * 32);
            bf16x8 b1 = ld8(Bb + 16 * 192 + ks * 32);
            #pragma unroll
            for (int ti = 0; ti < 4; ++ti) {
                acc[ti][0] = mfma16(a[ti][ks], b0, acc[ti][0]);
                acc[ti][1] = mfma16(a[ti][ks], b1, acc[ti][1]);
            }
        }
        #pragma unroll
        for (int ti = 0; ti < 4; ++ti)
            #pragma unroll
            for (int j = 0; j < 4; ++j) {
                int trow = m0 + wr * 64 + ti * 16 + hi * 4 + j;
                int w = trow >> 6, n = trow & 63;
                #pragma unroll
                for (int tj = 0; tj < 2; ++tj) {
                    int cw = cb0 + wc * 32 + tj * 16 + lo;   // 0..191 within section
                    int h = cw >> 5, d = cw & 31;
                    float val = acc[ti][tj][j] + bqkv[sect * 192 + cw];
                    long wh = (long)(w * 6 + h);
                    if (sect == 0)       qb[(wh * 64 + n) * 32 + d] = (bf16)(val * 0.17677669529663687f);
                    else if (sect == 1)  kb_[(wh * 64 + n) * 32 + d] = (bf16)val;
                    else                 vtb[(wh * 32 + d) * 64 + n] = (bf16)val;
                }
            }
    }
}

// ---------------- light attention: block=window, wave=head, no barriers ----------------
__global__ __launch_bounds__(384) void attn_light(
    const bf16* __restrict__ qb, const bf16* __restrict__ kb_,
    const bf16* __restrict__ vtb, const float* __restrict__ bias6,
    bf16* __restrict__ aw) {
    __shared__ char p_smem[6 * 8192];   // per head: [64][64] bf16 XOR-swizzled
    int w = blockIdx.x;
    int h = threadIdx.x >> 6;
    int lane = threadIdx.x & 63;
    int lo = lane & 15, hi = lane >> 4;
    char* ph = p_smem + h * 8192;
    long wh = (long)(w * 6 + h);
    f32x4 zf = {0.f, 0.f, 0.f, 0.f};

    bf16x8 qa[4], kb[4];
    #pragma unroll
    for (int ti = 0; ti < 4; ++ti) qa[ti] = ld8(qb  + (wh * 64 + ti * 16 + lo) * 32 + hi * 8);
    #pragma unroll
    for (int tj = 0; tj < 4; ++tj) kb[tj] = ld8(kb_ + (wh * 64 + tj * 16 + lo) * 32 + hi * 8);
    f32x4 s[4][4];
    #pragma unroll
    for (int ti = 0; ti < 4; ++ti)
        #pragma unroll
        for (int tj = 0; tj < 4; ++tj)
            s[ti][tj] = mfma16(qa[ti], kb[tj], zf);

    const float* bh = bias6 + h * 4096;
    #pragma unroll
    for (int ti = 0; ti < 4; ++ti)
        #pragma unroll
        for (int j = 0; j < 4; ++j) {
            int rr = ti * 16 + hi * 4 + j;
            float ev[4];
            #pragma unroll
            for (int tj = 0; tj < 4; ++tj) s[ti][tj][j] += bh[rr * 64 + tj * 16 + lo];
            float mx = fmaxf(fmaxf(s[ti][0][j], s[ti][1][j]), fmaxf(s[ti][2][j], s[ti][3][j]));
            #pragma unroll
            for (int m = 1; m < 16; m <<= 1) mx = fmaxf(mx, __shfl_xor(mx, m));
            float sum = 0.f;
            #pragma unroll
            for (int tj = 0; tj < 4; ++tj) { ev[tj] = __expf(s[ti][tj][j] - mx); sum += ev[tj]; }
            #pragma unroll
            for (int m = 1; m < 16; m <<= 1) sum += __shfl_xor(sum, m);
            float inv = 1.0f / sum;
            #pragma unroll
            for (int tj = 0; tj < 4; ++tj) {
                int byte = ((rr * 64 + tj * 16 + lo) * 2) ^ ((rr & 7) << 4);
                *(bf16*)(ph + byte) = (bf16)(ev[tj] * inv);
            }
        }

    f32x4 o[4][2];
    #pragma unroll
    for (int i = 0; i < 4; ++i) { o[i][0] = zf; o[i][1] = zf; }
    #pragma unroll
    for (int ks2 = 0; ks2 < 2; ++ks2) {
        bf16x8 pa[4], vb[2];
        #pragma unroll
        for (int ti = 0; ti < 4; ++ti) {
            int row = ti * 16 + lo;
            pa[ti] = *(const bf16x8*)(ph + ((row * 128 + ks2 * 64 + hi * 16) ^ ((row & 7) << 4)));
        }
        #pragma unroll
        for (int td = 0; td < 2; ++td)
            vb[td] = ld8(vtb + (wh * 32 + td * 16 + lo) * 64 + ks2 * 32 + hi * 8);
        #pragma unroll
        for (int ti = 0; ti < 4; ++ti)
            #pragma unroll
            for (int td = 0; td < 2; ++td)
                o[ti][td] = mfma16(pa[ti], vb[td], o[ti][td]);
    }
    bf16* orow = aw + (long)w * 64 * 192 + h * 32;
    #pragma unroll
    for (int ti = 0; ti < 4; ++ti)
        #pragma unroll
        for (int td = 0; td < 2; ++td)
            #pragma unroll
            for (int j = 0; j < 4; ++j)
                orow[(ti * 16 + hi * 4 + j) * 192 + td * 16 + lo] = (bf16)o[ti][td][j];
}

// ---------------- proj GEMM: A resident, 3 N-chunks, unwindow + residual (bf16 out1) ----------------
__global__ __launch_bounds__(256) void gemm_proj(
    const bf16* __restrict__ aw, const bf16* __restrict__ wt,
    const float* __restrict__ bias, const float* __restrict__ x,
    bf16* __restrict__ out1) {
    int m0 = blockIdx.x * 128;
    int wid = threadIdx.x >> 6, lane = threadIdx.x & 63;
    int wr = wid >> 1, wc = wid & 1;
    int lo = lane & 15, hi = lane >> 4;
    f32x4 zf = {0.f, 0.f, 0.f, 0.f};

    const bf16* Ab = aw + (long)(m0 + wr * 64 + lo) * 192 + hi * 8;
    bf16x8 a[4][6];
    #pragma unroll
    for (int ti = 0; ti < 4; ++ti)
        #pragma unroll
        for (int ks = 0; ks < 6; ++ks)
            a[ti][ks] = ld8(Ab + ti * 16 * 192 + ks * 32);

    #pragma unroll
    for (int nc = 0; nc < 3; ++nc) {
        f32x4 acc[4][2];
        #pragma unroll
        for (int i = 0; i < 4; ++i) { acc[i][0] = zf; acc[i][1] = zf; }
        const bf16* Bb = wt + (long)(nc * 64 + wc * 32 + lo) * 192 + hi * 8;
        #pragma unroll
        for (int ks = 0; ks < 6; ++ks) {
            bf16x8 b0 = ld8(Bb + ks * 32);
            bf16x8 b1 = ld8(Bb + 16 * 192 + ks * 32);
            #pragma unroll
            for (int ti = 0; ti < 4; ++ti) {
                acc[ti][0] = mfma16(a[ti][ks], b0, acc[ti][0]);
                acc[ti][1] = mfma16(a[ti][ks], b1, acc[ti][1]);
            }
        }
        #pragma unroll
        for (int ti = 0; ti < 4; ++ti)
            #pragma unroll
            for (int j = 0; j < 4; ++j) {
                int trow = m0 + wr * 64 + ti * 16 + hi * 4 + j;
                int wv = trow >> 6, n = trow & 63;
                int bb = wv / 1728; int rem = wv - bb * 1728;
                int dq = rem / 144; int rem2 = rem - dq * 144;
                int hq = rem2 / 12; int wq = rem2 - hq * 12;
                int l = (dq * 4 + (n >> 4)) * 2304 + (hq * 4 + ((n >> 2) & 3)) * 48 + (wq * 4 + (n & 3));
                long base = ((long)bb * L_TOT + l) * 192;
                #pragma unroll
                for (int tj = 0; tj < 2; ++tj) {
                    int col = nc * 64 + wc * 32 + tj * 16 + lo;
                    out1[base + col] = (bf16)(x[base + col] + acc[ti][tj][j] + bias[col]);
                }
            }
    }
}

// ---------------- fc1 GEMM: A resident, 6 N-chunks, transpose epilogue ----------------
__global__ __launch_bounds__(256) void gemm_fc1(
    const bf16* __restrict__ y, const bf16* __restrict__ wt,
    const float* __restrict__ bias, bf16* __restrict__ h_t) {
    __shared__ bf16 tl[64][136];
    int m0 = blockIdx.x * 128;
    int wid = threadIdx.x >> 6, lane = threadIdx.x & 63;
    int wr = wid >> 1, wc = wid & 1;
    int lo = lane & 15, hi = lane >> 4;
    f32x4 zf = {0.f, 0.f, 0.f, 0.f};
    int bb = m0 / L_TOT; int l0 = m0 - bb * L_TOT;
    int col = threadIdx.x >> 2, seg = threadIdx.x & 3;

    const bf16* Ab = y + (long)(m0 + wr * 64 + lo) * 192 + hi * 8;
    bf16x8 a[4][6];
    #pragma unroll
    for (int ti = 0; ti < 4; ++ti)
        #pragma unroll
        for (int ks = 0; ks < 6; ++ks)
            a[ti][ks] = ld8(Ab + ti * 16 * 192 + ks * 32);

    #pragma unroll
    for (int nc = 0; nc < 6; ++nc) {
        f32x4 acc[4][2];
        #pragma unroll
        for (int i = 0; i < 4; ++i) { acc[i][0] = zf; acc[i][1] = zf; }
        const bf16* Bb = wt + (long)(nc * 64 + wc * 32 + lo) * 192 + hi * 8;
        #pragma unroll
        for (int ks = 0; ks < 6; ++ks) {
            bf16x8 b0 = ld8(Bb + ks * 32);
            bf16x8 b1 = ld8(Bb + 16 * 192 + ks * 32);
            #pragma unroll
            for (int ti = 0; ti < 4; ++ti) {
                acc[ti][0] = mfma16(a[ti][ks], b0, acc[ti][0]);
                acc[ti][1] = mfma16(a[ti][ks], b1, acc[ti][1]);
            }
        }
        if (nc) __syncthreads();
        #pragma unroll
        for (int ti = 0; ti < 4; ++ti)
            #pragma unroll
            for (int tj = 0; tj < 2; ++tj)
                #pragma unroll
                for (int j = 0; j < 4; ++j) {
                    int rl = wr * 64 + ti * 16 + hi * 4 + j;
                    int cl = wc * 32 + tj * 16 + lo;
                    tl[cl][rl] = (bf16)(acc[ti][tj][j] + bias[nc * 64 + cl]);
                }
        __syncthreads();
        bf16* dst = h_t + ((long)bb * 384 + nc * 64 + col) * L_TOT + l0 + seg * 32;
        #pragma unroll
        for (int i8 = 0; i8 < 4; ++i8)
            *(bf16x8*)(dst + i8 * 8) = *(const bf16x8*)(&tl[col][seg * 32 + i8 * 8]);
    }
}

// ---------------- depthwise conv 3^3 + BN + GELU (chunk-vectorized) ----------------
__global__ __launch_bounds__(256) void dwconv_bn_gelu(
    const bf16* __restrict__ h_t, const float* __restrict__ wconv,
    const float* __restrict__ cb, const float* __restrict__ bng,
    const float* __restrict__ bnb, const float* __restrict__ bnm,
    const float* __restrict__ bnv, bf16* __restrict__ g_t) {
    __shared__ __align__(16) bf16 tile[10 * 2304];
    int blk = blockIdx.x;
    int bb = blk / 2304; int rem = blk - bb * 2304;
    int ch = rem / 6; int zb = rem - ch * 6; int z0 = zb * 8;
    const bf16* src = h_t + ((long)bb * 384 + ch) * L_TOT;
    for (int c = threadIdx.x; c < 2880; c += 256) {
        int e = c * 8; int zi = e / 2304; int off = e - zi * 2304;
        int gz = z0 - 1 + zi;
        uint4 val = make_uint4(0u, 0u, 0u, 0u);
        if (gz >= 0 && gz < 48) val = *(const uint4*)(src + (long)gz * 2304 + off);
        *(uint4*)(tile + e) = val;
    }
    float wgt[27];
    #pragma unroll
    for (int i = 0; i < 27; ++i) wgt[i] = wconv[ch * 27 + i];
    float scale = bng[ch] * rsqrtf(bnv[ch] + 1e-5f);
    float shift = bnb[ch] - bnm[ch] * scale;
    float cbias = cb[ch];
    __syncthreads();
    int lane = threadIdx.x & 63;
    bf16* dstc = g_t + ((long)bb * 384 + ch) * L_TOT + (long)z0 * 2304;
    #pragma unroll 1
    for (int u = 0; u < 9; ++u) {
        int unit = threadIdx.x + u * 256;       // consecutive lanes -> consecutive chunks
        int z = unit / 288; int c = unit - z * 288;
        int r = c / 6; int cx = c - r * 6; int x0 = cx * 8;
        float acc[8];
        #pragma unroll
        for (int i = 0; i < 8; ++i) acc[i] = 0.f;
        #pragma unroll
        for (int dz = 0; dz < 3; ++dz) {
            const bf16* plane = tile + (z + dz) * 2304;
            #pragma unroll
            for (int dy = 0; dy < 3; ++dy) {
                int ysr = r + dy - 1;
                bool vld = ((unsigned)ysr < 48u);
                const bf16* rp = plane + (vld ? ysr : 0) * 48 + x0;
                bf16x8 mv = ld8(rp);
                float m[8];
                #pragma unroll
                for (int i = 0; i < 8; ++i) m[i] = (float)mv[i];
                float lf = __shfl_up(m[7], 1);
                if (lane == 0 && cx > 0) lf = (float)rp[-1];
                if (cx == 0) lf = 0.f;
                float rf = __shfl_down(m[0], 1);
                if (lane == 63 && cx < 5) rf = (float)rp[8];
                if (cx == 5) rf = 0.f;
                float W0 = vld ? wgt[dz * 9 + dy * 3 + 0] : 0.f;
                float W1 = vld ? wgt[dz * 9 + dy * 3 + 1] : 0.f;
                float W2 = vld ? wgt[dz * 9 + dy * 3 + 2] : 0.f;
                acc[0] = fmaf(W0, lf,   fmaf(W1, m[0], fmaf(W2, m[1], acc[0])));
                #pragma unroll
                for (int xi = 1; xi < 7; ++xi)
                    acc[xi] = fmaf(W0, m[xi - 1], fmaf(W1, m[xi], fmaf(W2, m[xi + 1], acc[xi])));
                acc[7] = fmaf(W0, m[6], fmaf(W1, m[7], fmaf(W2, rf, acc[7])));
            }
        }
        bf16x8 ov;
        #pragma unroll
        for (int xi = 0; xi < 8; ++xi) {
            float v = acc[xi] + cbias;
            v = v * scale + shift;
            ov[xi] = (bf16)(0.5f * v * (1.0f + erff(v * 0.70710678118654752f)));
        }
        *(bf16x8*)(dstc + z * 2304 + r * 48 + x0) = ov;
    }
}

// ---------------- fc2 GEMM: 64-K tiles, double-buffered swizzled LDS, + residual ----------------
__global__ __launch_bounds__(256) void gemm_fc2(
    const bf16* __restrict__ g_t, const bf16* __restrict__ wt,
    const float* __restrict__ bias, const bf16* __restrict__ out1,
    float* __restrict__ out) {
    __shared__ bf16 As[2][8192];        // [128 tokens][64 ch], elem = tok*64 + (k ^ ((tok&7)<<3))
    int m0 = blockIdx.x * 128;
    int wid = threadIdx.x >> 6, lane = threadIdx.x & 63;
    int wr = wid >> 1, wc = wid & 1;
    int lo = lane & 15, hi = lane >> 4;
    int bb = m0 / L_TOT, l0 = m0 - bb * L_TOT;
    f32x4 zf = {0.f, 0.f, 0.f, 0.f};
    f32x4 acc[3][4][2];
    #pragma unroll
    for (int nc = 0; nc < 3; ++nc)
        #pragma unroll
        for (int i = 0; i < 4; ++i) { acc[nc][i][0] = zf; acc[nc][i][1] = zf; }

    int kk = threadIdx.x & 63, sg = threadIdx.x >> 6;   // stage: channel kk, tokens sg*32..+31
    const bf16* srcb = g_t + ((long)bb * 384 + kk) * L_TOT + l0 + sg * 32;

    bf16x8 r[4];
    #pragma unroll
    for (int p = 0; p < 4; ++p) r[p] = ld8(srcb + p * 8);
    #pragma unroll
    for (int p = 0; p < 4; ++p)
        #pragma unroll
        for (int i = 0; i < 8; ++i)
            As[0][(sg * 32 + p * 8 + i) * 64 + (kk ^ (i << 3))] = r[p][i];

    #pragma unroll
    for (int t = 0; t < 6; ++t) {
        __syncthreads();
        if (t < 5) {
            const bf16* s2 = srcb + (long)(t + 1) * 64 * L_TOT;
            #pragma unroll
            for (int p = 0; p < 4; ++p) r[p] = ld8(s2 + p * 8);
        }
        const bf16* Ac = As[t & 1];
        #pragma unroll
        for (int ksin = 0; ksin < 2; ++ksin) {
            bf16x8 a[4];
            #pragma unroll
            for (int ti = 0; ti < 4; ++ti) {
                int rr = wr * 64 + ti * 16 + lo;
                a[ti] = *(const bf16x8*)&Ac[rr * 64 + ((ksin * 32 + hi * 8) ^ ((rr & 7) << 3))];
            }
            #pragma unroll
            for (int nc = 0; nc < 3; ++nc) {
                bf16x8 b0 = ld8(wt + (long)(nc * 64 + wc * 32 + lo) * 384 + t * 64 + ksin * 32 + hi * 8);
                bf16x8 b1 = ld8(wt + (long)(nc * 64 + wc * 32 + 16 + lo) * 384 + t * 64 + ksin * 32 + hi * 8);
                #pragma unroll
                for (int ti = 0; ti < 4; ++ti) {
                    acc[nc][ti][0] = mfma16(a[ti], b0, acc[nc][ti][0]);
                    acc[nc][ti][1] = mfma16(a[ti], b1, acc[nc][ti][1]);
                }
            }
        }
        if (t < 5) {
            bf16* An = As[(t + 1) & 1];
            #pragma unroll
            for (int p = 0; p < 4; ++p)
                #pragma unroll
                for (int i = 0; i < 8; ++i)
                    An[(sg * 32 + p * 8 + i) * 64 + (kk ^ (i << 3))] = r[p][i];
        }
    }
    #pragma unroll
    for (int nc = 0; nc < 3; ++nc)
        #pragma unroll
        for (int ti = 0; ti < 4; ++ti)
            #pragma unroll
            for (int j = 0; j < 4; ++j) {
                long trow = m0 + wr * 64 + ti * 16 + hi * 4 + j;
                long base = trow * 192;
                #pragma unroll
                for (int tj = 0; tj < 2; ++tj) {
                    int col = nc * 64 + wc * 32 + tj * 16 + lo;
                    out[base + col] = (float)out1[base + col] + acc[nc][ti][tj][j] + bias[col];
                }
            }
}

// ---------------- host ----------------
extern "C" void kernel_launch(void* const* d_in, const int* in_sizes, int n_in,
                              void* d_out, int out_size, void* d_ws, size_t ws_size,
                              hipStream_t stream) {
    (void)in_sizes; (void)n_in; (void)out_size; (void)ws_size;
    const float* x     = (const float*)d_in[0];
    const float* ln1g  = (const float*)d_in[4];
    const float* ln1b  = (const float*)d_in[5];
    const float* ln2g  = (const float*)d_in[6];
    const float* ln2b  = (const float*)d_in[7];
    const float* qkvw  = (const float*)d_in[8];
    const float* qkvb  = (const float*)d_in[9];
    const float* rpb   = (const float*)d_in[10];
    const float* projw = (const float*)d_in[11];
    const float* projb = (const float*)d_in[12];
    const float* fc1w  = (const float*)d_in[13];
    const float* fc1b  = (const float*)d_in[14];
    const float* dww   = (const float*)d_in[15];
    const float* dwb   = (const float*)d_in[16];
    const float* bng   = (const float*)d_in[17];
    const float* bnb   = (const float*)d_in[18];
    const float* bnm   = (const float*)d_in[19];
    const float* bnv   = (const float*)d_in[20];
    const float* fc2w  = (const float*)d_in[21];
    const float* fc2b  = (const float*)d_in[22];
    float* out = (float*)d_out;

    char* ws = (char*)d_ws;
    size_t o = 0;
    bf16*  out1 = (bf16*)(ws + o);                           // bf16 [2][L][192] = 85MB
    bf16*  vt_buf = (bf16*)(ws + o + 84934656); o += 169869312;  // vt in 2nd half (disjoint)
    bf16*  h_t  = (bf16*)(ws + o); o += 169869312;           // bf16 [2][384][L] (doubles as q|k before fc1)
    bf16*  region1 = (bf16*)(ws + o); o += 169869312;        // xw|aw -> y -> g_t
    bf16*  xw  = region1;
    bf16*  aw  = region1 + 42467328;
    bf16*  yb  = region1;
    bf16*  g_t = region1;
    bf16*  qkvwt  = (bf16*)(ws + o); o += 221184;
    bf16*  projwt = (bf16*)(ws + o); o += 73728;
    bf16*  fc1wt  = (bf16*)(ws + o); o += 147456;
    bf16*  fc2wt  = (bf16*)(ws + o); o += 147456;
    float* bias6  = (float*)(ws + o); o += 98304;

    bf16* q_buf  = h_t;
    bf16* k_buf  = h_t + 42467328;

    wt_transpose<<<(110592 + 255) / 256, 256, 0, stream>>>(qkvw, qkvwt, 192, 576);
    wt_transpose<<<(36864 + 255) / 256, 256, 0, stream>>>(projw, projwt, 192, 192);
    wt_transpose<<<(73728 + 255) / 256, 256, 0, stream>>>(fc1w, fc1wt, 192, 384);
    wt_transpose<<<(73728 + 255) / 256, 256, 0, stream>>>(fc2w, fc2wt, 384, 192);
    bias6_build<<<96, 256, 0, stream>>>(rpb, bias6);

    ln1_window<<<55296, 256, 0, stream>>>(x, ln1g, ln1b, xw);
    gemm_qkv<<<1728, 256, 0, stream>>>(xw, qkvwt, qkvb, q_buf, k_buf, vt_buf);
    attn_light<<<NWIN, 384, 0, stream>>>(q_buf, k_buf, vt_buf, bias6, aw);
    gemm_proj<<<1728, 256, 0, stream>>>(aw, projwt, projb, x, out1);
    ln2_kernel<<<55296, 256, 0, stream>>>(out1, ln2g, ln2b, yb);
    gemm_fc1<<<1728, 256, 0, stream>>>(yb, fc1wt, fc1b, h_t);
    dwconv_bn_gelu<<<4608, 256, 0, stream>>>(h_t, dww, dwb, bng, bnb, bnm, bnv, g_t);
    gemm_fc2<<<1728, 256, 0, stream>>>(g_t, fc2wt, fc2b, out1, out);
}